// Round 3
// baseline (1143.412 us; speedup 1.0000x reference)
//
#include <hip/hip_runtime.h>
#include <hip/hip_fp16.h>

// GCN, 7 layers: h = relu(Â (h W) + b), Â = D^-1/2 (A + I) D^-1/2.
// Round 18: layer-1 matmul = round-0 compute structure + intra-block K-split.
//  Evidence so far: round-0 (NSPL=2, 48us) had the right FMA/W-path (VALU
//  16.5% = exactly the 8us FMA floor) but fetched X twice (99MB). NSPL=1
//  alone (round 16) halved bytes but with 1563 waves (1.5/SIMD) went
//  latency-bound at 434GB/s. LDS-staged K-split (round 17) died on s_load
//  serialization + scratch. Now: 128-thr block / 64 nodes; wave w keeps the
//  exact round-0 per-thread float4 ping-pong over k in [64w,64w+64) (acc[50],
//  3200 FMA/thread), then a 13.3KB LDS exchange (52-float pitch, rotated
//  banks): wave1 writes partials, wave0 adds + stores fp16. 3126 waves
//  (12/CU) + single X fetch. All other kernels: round-0 (477us) exact.

static constexpr int NN = 100000;
static constexpr int NE = 1600000;
static constexpr int BKL = 9;                      // 512 nodes per bucket
static constexpr int NBUK = (NN + 511) >> BKL;     // 196 buckets
static constexpr int EPT = 8;                      // edges per thread (hist/A1)
static constexpr int EB = (NE + 2047) / 2048;      // 782 edge blocks

typedef float f4v __attribute__((ext_vector_type(4)));

// ---------------- 1. bucket histogram (LDS only) ----------------

__global__ __launch_bounds__(256) void k_hist0(const int* __restrict__ col,
                                               int* __restrict__ counts) {
    __shared__ int lh[NBUK];
    for (int j = threadIdx.x; j < NBUK; j += 256) lh[j] = 0;
    __syncthreads();
    int base = blockIdx.x * 2048;
#pragma unroll
    for (int k = 0; k < EPT; ++k) {
        int e = base + k * 256 + threadIdx.x;
        if (e < NE) atomicAdd(&lh[col[e] >> BKL], 1);
    }
    __syncthreads();
    for (int j = threadIdx.x; j < NBUK; j += 256)
        counts[j * EB + blockIdx.x] = lh[j];  // bucket-major
}

// ---------------- 2a. per-bucket scan (196 parallel blocks) ----------------

__global__ __launch_bounds__(256) void k_scanA(int* __restrict__ counts,
                                               int* __restrict__ btot) {
    __shared__ int lds[256];
    const int b = blockIdx.x;
    const int t = threadIdx.x;
    int* c = counts + (size_t)b * EB;
    constexpr int PER = (EB + 255) / 256;  // 4
    int v[PER];
    int s = 0;
#pragma unroll
    for (int k = 0; k < PER; ++k) {
        int idx = t * PER + k;
        v[k] = (idx < EB) ? c[idx] : 0;
        s += v[k];
    }
    lds[t] = s;
    __syncthreads();
    for (int off = 1; off < 256; off <<= 1) {
        int u = (t >= off) ? lds[t - off] : 0;
        __syncthreads();
        lds[t] += u;
        __syncthreads();
    }
    int run = lds[t] - s;
#pragma unroll
    for (int k = 0; k < PER; ++k) {
        int idx = t * PER + k;
        if (idx < EB) { c[idx] = run; run += v[k]; }
    }
    if (t == 255) btot[b] = lds[255];
}

// ---------------- 2b. scan of 196 bucket totals -> bstart ----------------

__global__ void k_scanB(const int* __restrict__ btot, int* __restrict__ bstart) {
    __shared__ int lds[256];
    int t = threadIdx.x;
    int v = (t < NBUK) ? btot[t] : 0;
    lds[t] = v;
    __syncthreads();
    for (int off = 1; off < 256; off <<= 1) {
        int u = (t >= off) ? lds[t - off] : 0;
        __syncthreads();
        lds[t] += u;
        __syncthreads();
    }
    if (t < NBUK) bstart[t] = lds[t] - v;  // exclusive
    if (t == 0) bstart[NBUK] = NE;
}

// ---------------- 3. stage records, bucket-grouped (LDS cursors) ----------

__global__ __launch_bounds__(256) void k_A1(const int* __restrict__ row,
                                            const int* __restrict__ col,
                                            const float* __restrict__ ew,
                                            const int* __restrict__ counts,
                                            const int* __restrict__ bstart,
                                            int2* __restrict__ stg) {
    __shared__ int cur[NBUK];
    for (int j = threadIdx.x; j < NBUK; j += 256)
        cur[j] = bstart[j] + counts[j * EB + blockIdx.x];
    __syncthreads();
    int base = blockIdx.x * 2048;
#pragma unroll
    for (int k = 0; k < EPT; ++k) {
        int e = base + k * 256 + threadIdx.x;
        if (e < NE) {
            int c = col[e], r = row[e];
            int pos = atomicAdd(&cur[c >> BKL], 1);  // LDS atomic
            stg[pos] = make_int2(((c & 511) << 17) | r, __float_as_int(ew[e]));
        }
    }
}

// ---------------- 4. per-bucket degree -> dinv (plain stores) ----------

__global__ __launch_bounds__(256) void k_bdeg(const int* __restrict__ bstart,
                                              const int2* __restrict__ stg,
                                              float* __restrict__ dinv) {
    __shared__ float sdeg[512];
    const int b = blockIdx.x;
    for (int j = threadIdx.x; j < 512; j += 256) sdeg[j] = 0.0f;
    __syncthreads();
    const int s = bstart[b], e = bstart[b + 1];
    for (int p = s + threadIdx.x; p < e; p += 256) {
        int2 rec = stg[p];
        atomicAdd(&sdeg[rec.x >> 17], __int_as_float(rec.y));
    }
    __syncthreads();
    for (int j = threadIdx.x; j < 512; j += 256) {
        int idx = (b << BKL) + j;
        if (idx < NN) dinv[idx] = rsqrtf(sdeg[j] + 1.0f);  // +1 self-loop
    }
}

// ---------------- 5. per-bucket placement: offs + csw (LDS scan) ----------

__global__ __launch_bounds__(512) void k_place(const int* __restrict__ bstart,
                                               const int2* __restrict__ stg,
                                               const float* __restrict__ dinv,
                                               int* __restrict__ offs,
                                               int2* __restrict__ csw) {
    __shared__ int lcnt[512];
    __shared__ int cur[512];
    const int b = blockIdx.x;
    const int t = threadIdx.x;
    lcnt[t] = 0;
    __syncthreads();
    const int s = bstart[b], e = bstart[b + 1];
    for (int p = s + t; p < e; p += 512)
        atomicAdd(&lcnt[stg[p].x >> 17], 1);
    __syncthreads();
    int v = lcnt[t];
    for (int off = 1; off < 512; off <<= 1) {   // inclusive Hillis-Steele
        int u = (t >= off) ? lcnt[t - off] : 0;
        __syncthreads();
        lcnt[t] += u;
        __syncthreads();
    }
    int excl = lcnt[t] - v;
    int idx = (b << BKL) + t;
    if (idx <= NN) offs[idx] = s + excl;        // covers offs[NN] exactly once
    cur[t] = s + excl;
    __syncthreads();
    for (int p = s + t; p < e; p += 512) {
        int2 rec = stg[p];
        int cl = rec.x >> 17;
        int r = rec.x & 0x1FFFF;
        float nw = dinv[r] * __int_as_float(rec.y) * dinv[(b << BKL) + cl];
        int slot = atomicAdd(&cur[cl], 1);      // LDS atomic
        csw[slot] = make_int2(r, __float_as_int(nw));
    }
}

// ---------------- dense H = X * W, fp32 X (layer 1 only) ----------------
// 128 threads / 64 nodes; wave w computes k in [64w, 64w+64) with the
// round-0 per-thread float4 ping-pong (proven 2.45 TB/s effective + W on
// s_load path). Partials merged through a 52-float-pitch LDS buffer
// (13 granules -> rotated bank phase). X fetched exactly once.

#define FMA_GROUP(BUF, KBASE)                                          \
    _Pragma("unroll")                                                  \
    for (int g = 0; g < 4; ++g) {                                      \
        _Pragma("unroll")                                              \
        for (int kk = 0; kk < 4; ++kk) {                               \
            float xv = BUF[g][kk];                                     \
            const float* wrow = W + ((KBASE) + 4 * g + kk) * FOUT;     \
            _Pragma("unroll")                                          \
            for (int j = 0; j < FOUT; ++j)                             \
                acc[j] = fmaf(xv, wrow[j], acc[j]);                    \
        }                                                              \
    }

template <int FIN, int FOUT, int S>
__global__ __launch_bounds__(128, 2) void k_matmul_f(const float* __restrict__ X,
                                                     const float* __restrict__ W,
                                                     __half* __restrict__ H) {
    constexpr int KW = FIN / 2;                 // 64 k per wave
    constexpr int NG = KW / 16;                 // 4 groups of 16 floats
    constexpr int PITCH = 52;                   // floats; 13 granules, odd
    __shared__ __align__(16) float red[64 * PITCH];  // 13.3 KB
    const int t = threadIdx.x;
    const int w = t >> 6;
    const int lane = t & 63;
    const int node = blockIdx.x * 64 + lane;
    const bool valid = node < NN;
    // clamp row for tail block: no OOB, result discarded by store guard
    const float* xr = X + (size_t)(valid ? node : NN - 1) * FIN + w * KW;

    float acc[FOUT];
#pragma unroll
    for (int j = 0; j < FOUT; ++j) acc[j] = 0.0f;

    f4v bufA[4], bufB[4];
#pragma unroll
    for (int g = 0; g < 4; ++g) bufA[g] = *(const f4v*)(xr + 4 * g);
#pragma unroll 1
    for (int grp = 0; grp < NG; grp += 2) {
#pragma unroll
        for (int g = 0; g < 4; ++g) bufB[g] = *(const f4v*)(xr + (grp + 1) * 16 + 4 * g);
        FMA_GROUP(bufA, w * KW + grp * 16)
        if (grp + 2 < NG) {
#pragma unroll
            for (int g = 0; g < 4; ++g) bufA[g] = *(const f4v*)(xr + (grp + 2) * 16 + 4 * g);
        }
        FMA_GROUP(bufB, w * KW + (grp + 1) * 16)
    }

    // cross-wave reduce: wave1 -> LDS, wave0 adds + stores fp16
    if (w == 1) {
        float* r = red + lane * PITCH;
#pragma unroll
        for (int jj = 0; jj < FOUT / 4; ++jj) {
            f4v v = {acc[4 * jj], acc[4 * jj + 1], acc[4 * jj + 2], acc[4 * jj + 3]};
            *(f4v*)(r + 4 * jj) = v;
        }
#pragma unroll
        for (int j = (FOUT / 4) * 4; j < FOUT; ++j) r[j] = acc[j];
    }
    __syncthreads();
    if (w == 0 && valid) {
        const float* r = red + lane * PITCH;
#pragma unroll
        for (int jj = 0; jj < FOUT / 4; ++jj) {
            f4v v = *(const f4v*)(r + 4 * jj);
#pragma unroll
            for (int e = 0; e < 4; ++e) acc[4 * jj + e] += v[e];
        }
#pragma unroll
        for (int j = (FOUT / 4) * 4; j < FOUT; ++j) acc[j] += r[j];

        __half2 hv[FOUT / 2];
#pragma unroll
        for (int j = 0; j < FOUT / 2; ++j)
            hv[j] = __floats2half2_rn(acc[2 * j], acc[2 * j + 1]);
        __half* hr = H + (size_t)node * S;
#pragma unroll
        for (int c = 0; c < FOUT / 8; ++c) *(int4*)(hr + 8 * c) = ((const int4*)hv)[c];
#pragma unroll
        for (int j = (FOUT / 8) * 4; j < FOUT / 2; ++j) *(__half2*)(hr + 2 * j) = hv[j];
    }
}
#undef FMA_GROUP

// ---------------- dense H = X * W, fp16 X (layers 2..6) ----------------
// Round-0 configuration: 256-thr blocks, NSPL output split, all chunk
// loads issued upfront (<=7 independent int4s in flight), then pure FMA.

template <int FIN, int SX, int FOUT, int S, int NSPL>
__global__ __launch_bounds__(256, 2) void k_matmul_h(const __half* __restrict__ X,
                                                     const float* __restrict__ W,
                                                     __half* __restrict__ H) {
    constexpr int FC = FOUT / NSPL;
    constexpr int NCH = (FIN + 7) / 8;
    const int node = blockIdx.x * 256 + threadIdx.x;
    const int ch = blockIdx.y;                 // SGPR by construction
    if (node >= NN) return;
    const __half* xr = X + (size_t)node * SX;
    int4 raw[NCH];
#pragma unroll
    for (int c = 0; c < NCH; ++c) raw[c] = *(const int4*)(xr + 8 * c);
    float acc[FC];
#pragma unroll
    for (int j = 0; j < FC; ++j) acc[j] = 0.0f;
#pragma unroll
    for (int c = 0; c < NCH; ++c) {
        const __half2* hp = (const __half2*)&raw[c];
        const int lim = (FIN - 8 * c < 8) ? FIN - 8 * c : 8;  // folds post-unroll
#pragma unroll
        for (int kk = 0; kk < 8; ++kk) {
            if (kk < lim) {
                __half2 pair = hp[kk >> 1];
                float xv = (kk & 1) ? __high2float(pair) : __low2float(pair);
                const float* wrow = W + (8 * c + kk) * FOUT + ch * FC;
#pragma unroll
                for (int j = 0; j < FC; ++j) acc[j] = fmaf(xv, wrow[j], acc[j]);
            }
        }
    }
    __half* hr = H + (size_t)node * S + ch * FC;
#pragma unroll
    for (int j = 0; j < FC; ++j) hr[j] = __float2half_rn(acc[j]);
}

// layer 7: 10 -> 1, fp16 X (stride 16), fp32 H out
__global__ void k_matmul_1h(const __half* __restrict__ X, const float* __restrict__ W,
                            float* __restrict__ H) {
    int i = blockIdx.x * blockDim.x + threadIdx.x;
    if (i >= NN) return;
    const __half* xr = X + (size_t)i * 16;
    int4 r0 = *(const int4*)xr;                  // halfs 0..7
    __half2 r1 = *(const __half2*)(xr + 8);      // halfs 8,9
    const __half2* hp = (const __half2*)&r0;
    float acc = 0.0f;
#pragma unroll
    for (int q = 0; q < 4; ++q) {
        acc = fmaf(__low2float(hp[q]), W[2 * q], acc);
        acc = fmaf(__high2float(hp[q]), W[2 * q + 1], acc);
    }
    acc = fmaf(__low2float(r1), W[8], acc);
    acc = fmaf(__high2float(r1), W[9], acc);
    H[i] = acc;
}

// ---------------- CSR pull aggregation + fused epilogue (fp16 H) ----------
// Lane handles 4 half2s (one 16B gather per edge). Output stored fp16 at
// stride SA halfs (the next layer's X). csw records read nontemporal.

static __device__ __forceinline__ int2 nt_load2(const int2* p) {
    unsigned long long raw = __builtin_nontemporal_load((const unsigned long long*)p);
    return make_int2((int)(raw & 0xFFFFFFFFull), (int)(raw >> 32));
}

template <int F, int SH, int SA, int LPN, bool RELU>
__global__ __launch_bounds__(256) void k_agg2(const int* __restrict__ offs,
                                              const int2* __restrict__ csw,
                                              const __half2* __restrict__ H,
                                              const float* __restrict__ dinv,
                                              const float* __restrict__ b,
                                              __half* __restrict__ O) {
    constexpr int R = F / 2;               // real half2 count per row
    int t = blockIdx.x * blockDim.x + threadIdx.x;
    int g = t / LPN;
    int f = t - g * LPN;
    if (g >= NN) return;
    const int q0 = 4 * f;                  // first half2 this lane owns
    if (q0 >= R) return;                   // fully-pad lane: idle
    int p = offs[g];
    const int pe = offs[g + 1];
    const int pl = pe - 1;

    float2 acc[4];
#pragma unroll
    for (int c = 0; c < 4; ++c) acc[c] = make_float2(0.f, 0.f);

    for (; p < pe; p += 4) {
        int2 e[4];
#pragma unroll
        for (int i = 0; i < 4; ++i) e[i] = nt_load2(csw + min(p + i, pl));
        __half2 h[4][4];
#pragma unroll
        for (int i = 0; i < 4; ++i)
            *(int4*)h[i] = *(const int4*)(H + (size_t)e[i].x * SH + q0);
#pragma unroll
        for (int i = 0; i < 4; ++i) {
            float w = (p + i < pe) ? __int_as_float(e[i].y) : 0.0f;
#pragma unroll
            for (int c = 0; c < 4; ++c) {
                acc[c].x = fmaf(__low2float(h[i][c]), w, acc[c].x);
                acc[c].y = fmaf(__high2float(h[i][c]), w, acc[c].y);
            }
        }
    }

    float di = dinv[g];
    float d2 = di * di;
    __half2 hs[4];
    *(int4*)hs = *(const int4*)(H + (size_t)g * SH + q0);
    __half2* orow = (__half2*)(O + (size_t)g * SA) + q0;
#pragma unroll
    for (int c = 0; c < 4; ++c) {
        if (q0 + c < R) {
            float vx = acc[c].x + fmaf(__low2float(hs[c]), d2, b[2 * (q0 + c)]);
            float vy = acc[c].y + fmaf(__high2float(hs[c]), d2, b[2 * (q0 + c) + 1]);
            if (RELU) { vx = fmaxf(vx, 0.f); vy = fmaxf(vy, 0.f); }
            orow[c] = __floats2half2_rn(vx, vy);
        }
    }
}

// F=1 aggregation (final layer, fp32 H): one thread per node, predicated 4-wide.
__global__ void k_agg1(const int* __restrict__ offs, const int2* __restrict__ csw,
                       const float* __restrict__ H, const float* __restrict__ dinv,
                       const float* __restrict__ b, float* __restrict__ O) {
    int g = blockIdx.x * blockDim.x + threadIdx.x;
    if (g >= NN) return;
    int p = offs[g];
    const int pe = offs[g + 1];
    const int pl = pe - 1;
    float a0 = 0.f, a1 = 0.f, a2 = 0.f, a3 = 0.f;
    for (; p < pe; p += 4) {
        int2 e0 = nt_load2(csw + min(p, pl)),     e1 = nt_load2(csw + min(p + 1, pl));
        int2 e2 = nt_load2(csw + min(p + 2, pl)), e3 = nt_load2(csw + min(p + 3, pl));
        float w0 = (p < pe)     ? __int_as_float(e0.y) : 0.f;
        float w1 = (p + 1 < pe) ? __int_as_float(e1.y) : 0.f;
        float w2 = (p + 2 < pe) ? __int_as_float(e2.y) : 0.f;
        float w3 = (p + 3 < pe) ? __int_as_float(e3.y) : 0.f;
        a0 = fmaf(H[e0.x], w0, a0);
        a1 = fmaf(H[e1.x], w1, a1);
        a2 = fmaf(H[e2.x], w2, a2);
        a3 = fmaf(H[e3.x], w3, a3);
    }
    float di = dinv[g];
    O[g] = ((a0 + a1) + (a2 + a3)) + fmaf(H[g], di * di, b[0]);
}

// ---------------- launch ----------------

static inline size_t alignup(size_t x) { return (x + 255) & ~(size_t)255; }

extern "C" void kernel_launch(void* const* d_in, const int* in_sizes, int n_in,
                              void* d_out, int out_size, void* d_ws, size_t ws_size,
                              hipStream_t stream) {
    const float* x  = (const float*)d_in[0];
    const int*   ei = (const int*)d_in[1];
    const float* ew = (const float*)d_in[2];
    const float* Wp[7];
    const float* Bp[7];
    for (int l = 0; l < 7; ++l) {
        Wp[l] = (const float*)d_in[3 + 2 * l];
        Bp[l] = (const float*)d_in[4 + 2 * l];
    }
    const int* row = ei;       // source
    const int* col = ei + NE;  // destination

    // workspace carve (~70 MB); Hb/Aa/Ab fp16, stride <= 64 halfs
    char* ws = (char*)d_ws;
    float* dinv  = (float*)ws;  ws += alignup((size_t)NN * 4);
    char*  Hb    = ws;          ws += alignup((size_t)NN * 64 * 2);
    char*  Aa    = ws;          ws += alignup((size_t)NN * 64 * 2);
    char*  Ab    = ws;          ws += alignup((size_t)NN * 64 * 2);
    int*   offs  = (int*)ws;    ws += alignup((size_t)(NN + 1) * 4);
    int*   counts= (int*)ws;    ws += alignup((size_t)NBUK * EB * 4);
    int*   btot  = (int*)ws;    ws += alignup((size_t)NBUK * 4);
    int*   bstart= (int*)ws;    ws += alignup((size_t)(NBUK + 1) * 4);
    int2*  stg   = (int2*)ws;   ws += alignup((size_t)NE * 8);
    int2*  csw   = (int2*)ws;   ws += alignup((size_t)NE * 8);

    const int gN  = (NN + 255) / 256;
    const int gB  = (NN + 63) / 64;    // 64-node tiles for the L1 matmul

    // CSR build — no global atomics, no single-block O(N) scans
    k_hist0<<<EB, 256, 0, stream>>>(col, counts);
    k_scanA<<<NBUK, 256, 0, stream>>>(counts, btot);
    k_scanB<<<1, 256, 0, stream>>>(btot, bstart);
    k_A1<<<EB, 256, 0, stream>>>(row, col, ew, counts, bstart, stg);
    k_bdeg<<<NBUK, 256, 0, stream>>>(bstart, stg, dinv);
    k_place<<<NBUK, 512, 0, stream>>>(bstart, stg, dinv, offs, csw);

#define AGG(FOUT, S, LPN, RELU, OUT, LIDX)                                                  \
    k_agg2<FOUT, (S) / 2, S, LPN, RELU>                                                     \
        <<<((size_t)NN * (LPN) + 255) / 256, 256, 0, stream>>>(                             \
            offs, csw, (const __half2*)Hb, dinv, Bp[LIDX], (__half*)(OUT))

    // layer 1: fp32 x input, intra-block K-split (X fetched once)
    k_matmul_f<128, 50, 64><<<gB, 128, 0, stream>>>(x, Wp[0], (__half*)Hb);
    AGG(50, 64, 8, true, Aa, 0);
    // layers 2..6: fp16 activations in (round-0 NSPL configuration)
    k_matmul_h<50, 64, 50, 64, 2><<<dim3(gN, 2), 256, 0, stream>>>((const __half*)Aa, Wp[1], (__half*)Hb);
    AGG(50, 64, 8, true, Ab, 1);
    k_matmul_h<50, 64, 30, 32, 2><<<dim3(gN, 2), 256, 0, stream>>>((const __half*)Ab, Wp[2], (__half*)Hb);
    AGG(30, 32, 4, true, Aa, 2);
    k_matmul_h<30, 32, 30, 32, 2><<<dim3(gN, 2), 256, 0, stream>>>((const __half*)Aa, Wp[3], (__half*)Hb);
    AGG(30, 32, 4, true, Ab, 3);
    k_matmul_h<30, 32, 10, 16, 1><<<dim3(gN, 1), 256, 0, stream>>>((const __half*)Ab, Wp[4], (__half*)Hb);
    AGG(10, 16, 2, true, Aa, 4);
    k_matmul_h<10, 16, 10, 16, 1><<<dim3(gN, 1), 256, 0, stream>>>((const __half*)Aa, Wp[5], (__half*)Hb);
    AGG(10, 16, 2, true, Ab, 5);
#undef AGG

    // layer 7: 10 -> 1, no relu, fp32 H, fp32 output
    k_matmul_1h<<<gN, 256, 0, stream>>>((const __half*)Ab, Wp[6], (float*)Hb);
    k_agg1<<<gN, 256, 0, stream>>>(offs, csw, (const float*)Hb, dinv, Bp[6],
                                   (float*)d_out);
}

// Round 5
// 482.512 us; speedup vs baseline: 2.3697x; 2.3697x over previous
//
#include <hip/hip_runtime.h>
#include <hip/hip_fp16.h>

// GCN, 7 layers: h = relu(Â (h W) + b), Â = D^-1/2 (A + I) D^-1/2.
// Round 20 (= round 19 resubmit; previous bench died on container acquire,
// not on the kernel). Full round-15 (477.9us measured) configuration, with
// ONE change: k_matmul_f grid flattened (391,2) -> 782 so the two
// output-chunk blocks that read the SAME 256 X rows are adjacent in dispatch
// order. Round-15 counters showed FETCH 99MB = X streamed from HBM twice
// (y=0 wavefront finishes ~391 blocks before y=1 starts -> no L3 reuse).
// Adjacent pairing puts the second reader ~us behind the first -> L2/L3 hit.
// ch = blockIdx.x & 1 stays SGPR-uniform -> W remains on the s_load path.
// Lessons burned into rounds 16-18: rewrites of this kernel break one of
// {wave count, register budget (spill!), W s_load path} — do not rewrite.

static constexpr int NN = 100000;
static constexpr int NE = 1600000;
static constexpr int BKL = 9;                      // 512 nodes per bucket
static constexpr int NBUK = (NN + 511) >> BKL;     // 196 buckets
static constexpr int EPT = 8;                      // edges per thread (hist/A1)
static constexpr int EB = (NE + 2047) / 2048;      // 782 edge blocks

// ---------------- 1. bucket histogram (LDS only) ----------------

__global__ __launch_bounds__(256) void k_hist0(const int* __restrict__ col,
                                               int* __restrict__ counts) {
    __shared__ int lh[NBUK];
    for (int j = threadIdx.x; j < NBUK; j += 256) lh[j] = 0;
    __syncthreads();
    int base = blockIdx.x * 2048;
#pragma unroll
    for (int k = 0; k < EPT; ++k) {
        int e = base + k * 256 + threadIdx.x;
        if (e < NE) atomicAdd(&lh[col[e] >> BKL], 1);
    }
    __syncthreads();
    for (int j = threadIdx.x; j < NBUK; j += 256)
        counts[j * EB + blockIdx.x] = lh[j];  // bucket-major
}

// ---------------- 2a. per-bucket scan (196 parallel blocks) ----------------

__global__ __launch_bounds__(256) void k_scanA(int* __restrict__ counts,
                                               int* __restrict__ btot) {
    __shared__ int lds[256];
    const int b = blockIdx.x;
    const int t = threadIdx.x;
    int* c = counts + (size_t)b * EB;
    constexpr int PER = (EB + 255) / 256;  // 4
    int v[PER];
    int s = 0;
#pragma unroll
    for (int k = 0; k < PER; ++k) {
        int idx = t * PER + k;
        v[k] = (idx < EB) ? c[idx] : 0;
        s += v[k];
    }
    lds[t] = s;
    __syncthreads();
    for (int off = 1; off < 256; off <<= 1) {
        int u = (t >= off) ? lds[t - off] : 0;
        __syncthreads();
        lds[t] += u;
        __syncthreads();
    }
    int run = lds[t] - s;
#pragma unroll
    for (int k = 0; k < PER; ++k) {
        int idx = t * PER + k;
        if (idx < EB) { c[idx] = run; run += v[k]; }
    }
    if (t == 255) btot[b] = lds[255];
}

// ---------------- 2b. scan of 196 bucket totals -> bstart ----------------

__global__ void k_scanB(const int* __restrict__ btot, int* __restrict__ bstart) {
    __shared__ int lds[256];
    int t = threadIdx.x;
    int v = (t < NBUK) ? btot[t] : 0;
    lds[t] = v;
    __syncthreads();
    for (int off = 1; off < 256; off <<= 1) {
        int u = (t >= off) ? lds[t - off] : 0;
        __syncthreads();
        lds[t] += u;
        __syncthreads();
    }
    if (t < NBUK) bstart[t] = lds[t] - v;  // exclusive
    if (t == 0) bstart[NBUK] = NE;
}

// ---------------- 3. stage records, bucket-grouped (LDS cursors) ----------

__global__ __launch_bounds__(256) void k_A1(const int* __restrict__ row,
                                            const int* __restrict__ col,
                                            const float* __restrict__ ew,
                                            const int* __restrict__ counts,
                                            const int* __restrict__ bstart,
                                            int2* __restrict__ stg) {
    __shared__ int cur[NBUK];
    for (int j = threadIdx.x; j < NBUK; j += 256)
        cur[j] = bstart[j] + counts[j * EB + blockIdx.x];
    __syncthreads();
    int base = blockIdx.x * 2048;
#pragma unroll
    for (int k = 0; k < EPT; ++k) {
        int e = base + k * 256 + threadIdx.x;
        if (e < NE) {
            int c = col[e], r = row[e];
            int pos = atomicAdd(&cur[c >> BKL], 1);  // LDS atomic
            stg[pos] = make_int2(((c & 511) << 17) | r, __float_as_int(ew[e]));
        }
    }
}

// ---------------- 4. per-bucket degree -> dinv (plain stores) ----------

__global__ __launch_bounds__(256) void k_bdeg(const int* __restrict__ bstart,
                                              const int2* __restrict__ stg,
                                              float* __restrict__ dinv) {
    __shared__ float sdeg[512];
    const int b = blockIdx.x;
    for (int j = threadIdx.x; j < 512; j += 256) sdeg[j] = 0.0f;
    __syncthreads();
    const int s = bstart[b], e = bstart[b + 1];
    for (int p = s + threadIdx.x; p < e; p += 256) {
        int2 rec = stg[p];
        atomicAdd(&sdeg[rec.x >> 17], __int_as_float(rec.y));
    }
    __syncthreads();
    for (int j = threadIdx.x; j < 512; j += 256) {
        int idx = (b << BKL) + j;
        if (idx < NN) dinv[idx] = rsqrtf(sdeg[j] + 1.0f);  // +1 self-loop
    }
}

// ---------------- 5. per-bucket placement: offs + csw (LDS scan) ----------

__global__ __launch_bounds__(512) void k_place(const int* __restrict__ bstart,
                                               const int2* __restrict__ stg,
                                               const float* __restrict__ dinv,
                                               int* __restrict__ offs,
                                               int2* __restrict__ csw) {
    __shared__ int lcnt[512];
    __shared__ int cur[512];
    const int b = blockIdx.x;
    const int t = threadIdx.x;
    lcnt[t] = 0;
    __syncthreads();
    const int s = bstart[b], e = bstart[b + 1];
    for (int p = s + t; p < e; p += 512)
        atomicAdd(&lcnt[stg[p].x >> 17], 1);
    __syncthreads();
    int v = lcnt[t];
    for (int off = 1; off < 512; off <<= 1) {   // inclusive Hillis-Steele
        int u = (t >= off) ? lcnt[t - off] : 0;
        __syncthreads();
        lcnt[t] += u;
        __syncthreads();
    }
    int excl = lcnt[t] - v;
    int idx = (b << BKL) + t;
    if (idx <= NN) offs[idx] = s + excl;        // covers offs[NN] exactly once
    cur[t] = s + excl;
    __syncthreads();
    for (int p = s + t; p < e; p += 512) {
        int2 rec = stg[p];
        int cl = rec.x >> 17;
        int r = rec.x & 0x1FFFF;
        float nw = dinv[r] * __int_as_float(rec.y) * dinv[(b << BKL) + cl];
        int slot = atomicAdd(&cur[cl], 1);      // LDS atomic
        csw[slot] = make_int2(r, __float_as_int(nw));
    }
}

// ---------------- dense H = X * W, fp32 X (layer 1 only) ----------------
// blockIdx.x & 1 = output chunk (SGPR-uniform -> W on s_load path); paired
// blocks read the same X rows back-to-back -> second read hits L2/L3.
// Explicit 2-stage pipeline: double-buffered groups of 4 float4s, 4 loads
// in flight while 400 FMAs retire. (Round-15 body, grid flattened.)

template <int FIN, int FOUT, int S, int NSPL>
__global__ __launch_bounds__(256, 2) void k_matmul_f(const float* __restrict__ X,
                                                     const float* __restrict__ W,
                                                     __half* __restrict__ H) {
    constexpr int FC = FOUT / NSPL;
    constexpr int NG = FIN / 16;               // groups of 16 floats
    const int node = (blockIdx.x >> 1) * 256 + threadIdx.x;
    const int ch = blockIdx.x & 1;             // SGPR by construction
    if (node >= NN) return;
    const float* xr = X + (size_t)node * FIN;
    float acc[FC];
#pragma unroll
    for (int j = 0; j < FC; ++j) acc[j] = 0.0f;

    float4 buf[2][4];
#pragma unroll
    for (int g = 0; g < 4; ++g) buf[0][g] = *(const float4*)(xr + 4 * g);
#pragma unroll
    for (int grp = 0; grp < NG; ++grp) {
        const int cur = grp & 1;
        if (grp + 1 < NG) {
#pragma unroll
            for (int g = 0; g < 4; ++g)
                buf[cur ^ 1][g] = *(const float4*)(xr + (grp + 1) * 16 + 4 * g);
        }
#pragma unroll
        for (int g = 0; g < 4; ++g)
#pragma unroll
            for (int kk = 0; kk < 4; ++kk) {
                float xv = ((const float*)&buf[cur][g])[kk];
                const float* wrow = W + (grp * 16 + 4 * g + kk) * FOUT + ch * FC;
#pragma unroll
                for (int j = 0; j < FC; ++j) acc[j] = fmaf(xv, wrow[j], acc[j]);
            }
    }
    __half* hr = H + (size_t)node * S + ch * FC;
#pragma unroll
    for (int j = 0; j < FC; ++j) hr[j] = __float2half_rn(acc[j]);
}

// ---------------- dense H = X * W, fp16 X (layers 2..6) ----------------
// All chunk loads issued upfront (<=7 independent int4s in flight), then
// pure FMA. Pad halfs beyond FIN are loaded but never used (bounded kk).

template <int FIN, int SX, int FOUT, int S, int NSPL>
__global__ __launch_bounds__(256, 2) void k_matmul_h(const __half* __restrict__ X,
                                                     const float* __restrict__ W,
                                                     __half* __restrict__ H) {
    constexpr int FC = FOUT / NSPL;
    constexpr int NCH = (FIN + 7) / 8;
    const int node = blockIdx.x * 256 + threadIdx.x;
    const int ch = blockIdx.y;                 // SGPR by construction
    if (node >= NN) return;
    const __half* xr = X + (size_t)node * SX;
    int4 raw[NCH];
#pragma unroll
    for (int c = 0; c < NCH; ++c) raw[c] = *(const int4*)(xr + 8 * c);
    float acc[FC];
#pragma unroll
    for (int j = 0; j < FC; ++j) acc[j] = 0.0f;
#pragma unroll
    for (int c = 0; c < NCH; ++c) {
        const __half2* hp = (const __half2*)&raw[c];
        const int lim = (FIN - 8 * c < 8) ? FIN - 8 * c : 8;  // folds post-unroll
#pragma unroll
        for (int kk = 0; kk < 8; ++kk) {
            if (kk < lim) {
                __half2 pair = hp[kk >> 1];
                float xv = (kk & 1) ? __high2float(pair) : __low2float(pair);
                const float* wrow = W + (8 * c + kk) * FOUT + ch * FC;
#pragma unroll
                for (int j = 0; j < FC; ++j) acc[j] = fmaf(xv, wrow[j], acc[j]);
            }
        }
    }
    __half* hr = H + (size_t)node * S + ch * FC;
#pragma unroll
    for (int j = 0; j < FC; ++j) hr[j] = __float2half_rn(acc[j]);
}

// layer 7: 10 -> 1, fp16 X (stride 16), fp32 H out
__global__ void k_matmul_1h(const __half* __restrict__ X, const float* __restrict__ W,
                            float* __restrict__ H) {
    int i = blockIdx.x * blockDim.x + threadIdx.x;
    if (i >= NN) return;
    const __half* xr = X + (size_t)i * 16;
    int4 r0 = *(const int4*)xr;                  // halfs 0..7
    __half2 r1 = *(const __half2*)(xr + 8);      // halfs 8,9
    const __half2* hp = (const __half2*)&r0;
    float acc = 0.0f;
#pragma unroll
    for (int q = 0; q < 4; ++q) {
        acc = fmaf(__low2float(hp[q]), W[2 * q], acc);
        acc = fmaf(__high2float(hp[q]), W[2 * q + 1], acc);
    }
    acc = fmaf(__low2float(r1), W[8], acc);
    acc = fmaf(__high2float(r1), W[9], acc);
    H[i] = acc;
}

// ---------------- CSR pull aggregation + fused epilogue (fp16 H) ----------
// Lane handles 4 half2s (one 16B gather per edge). Output stored fp16 at
// stride SA halfs (the next layer's X). csw records read nontemporal.

static __device__ __forceinline__ int2 nt_load2(const int2* p) {
    unsigned long long raw = __builtin_nontemporal_load((const unsigned long long*)p);
    return make_int2((int)(raw & 0xFFFFFFFFull), (int)(raw >> 32));
}

template <int F, int SH, int SA, int LPN, bool RELU>
__global__ __launch_bounds__(256) void k_agg2(const int* __restrict__ offs,
                                              const int2* __restrict__ csw,
                                              const __half2* __restrict__ H,
                                              const float* __restrict__ dinv,
                                              const float* __restrict__ b,
                                              __half* __restrict__ O) {
    constexpr int R = F / 2;               // real half2 count per row
    int t = blockIdx.x * blockDim.x + threadIdx.x;
    int g = t / LPN;
    int f = t - g * LPN;
    if (g >= NN) return;
    const int q0 = 4 * f;                  // first half2 this lane owns
    if (q0 >= R) return;                   // fully-pad lane: idle
    int p = offs[g];
    const int pe = offs[g + 1];
    const int pl = pe - 1;

    float2 acc[4];
#pragma unroll
    for (int c = 0; c < 4; ++c) acc[c] = make_float2(0.f, 0.f);

    for (; p < pe; p += 4) {
        int2 e[4];
#pragma unroll
        for (int i = 0; i < 4; ++i) e[i] = nt_load2(csw + min(p + i, pl));
        __half2 h[4][4];
#pragma unroll
        for (int i = 0; i < 4; ++i)
            *(int4*)h[i] = *(const int4*)(H + (size_t)e[i].x * SH + q0);
#pragma unroll
        for (int i = 0; i < 4; ++i) {
            float w = (p + i < pe) ? __int_as_float(e[i].y) : 0.0f;
#pragma unroll
            for (int c = 0; c < 4; ++c) {
                acc[c].x = fmaf(__low2float(h[i][c]), w, acc[c].x);
                acc[c].y = fmaf(__high2float(h[i][c]), w, acc[c].y);
            }
        }
    }

    float di = dinv[g];
    float d2 = di * di;
    __half2 hs[4];
    *(int4*)hs = *(const int4*)(H + (size_t)g * SH + q0);
    __half2* orow = (__half2*)(O + (size_t)g * SA) + q0;
#pragma unroll
    for (int c = 0; c < 4; ++c) {
        if (q0 + c < R) {
            float vx = acc[c].x + fmaf(__low2float(hs[c]), d2, b[2 * (q0 + c)]);
            float vy = acc[c].y + fmaf(__high2float(hs[c]), d2, b[2 * (q0 + c) + 1]);
            if (RELU) { vx = fmaxf(vx, 0.f); vy = fmaxf(vy, 0.f); }
            orow[c] = __floats2half2_rn(vx, vy);
        }
    }
}

// F=1 aggregation (final layer, fp32 H): one thread per node, predicated 4-wide.
__global__ void k_agg1(const int* __restrict__ offs, const int2* __restrict__ csw,
                       const float* __restrict__ H, const float* __restrict__ dinv,
                       const float* __restrict__ b, float* __restrict__ O) {
    int g = blockIdx.x * blockDim.x + threadIdx.x;
    if (g >= NN) return;
    int p = offs[g];
    const int pe = offs[g + 1];
    const int pl = pe - 1;
    float a0 = 0.f, a1 = 0.f, a2 = 0.f, a3 = 0.f;
    for (; p < pe; p += 4) {
        int2 e0 = nt_load2(csw + min(p, pl)),     e1 = nt_load2(csw + min(p + 1, pl));
        int2 e2 = nt_load2(csw + min(p + 2, pl)), e3 = nt_load2(csw + min(p + 3, pl));
        float w0 = (p < pe)     ? __int_as_float(e0.y) : 0.f;
        float w1 = (p + 1 < pe) ? __int_as_float(e1.y) : 0.f;
        float w2 = (p + 2 < pe) ? __int_as_float(e2.y) : 0.f;
        float w3 = (p + 3 < pe) ? __int_as_float(e3.y) : 0.f;
        a0 = fmaf(H[e0.x], w0, a0);
        a1 = fmaf(H[e1.x], w1, a1);
        a2 = fmaf(H[e2.x], w2, a2);
        a3 = fmaf(H[e3.x], w3, a3);
    }
    float di = dinv[g];
    O[g] = ((a0 + a1) + (a2 + a3)) + fmaf(H[g], di * di, b[0]);
}

// ---------------- launch ----------------

static inline size_t alignup(size_t x) { return (x + 255) & ~(size_t)255; }

extern "C" void kernel_launch(void* const* d_in, const int* in_sizes, int n_in,
                              void* d_out, int out_size, void* d_ws, size_t ws_size,
                              hipStream_t stream) {
    const float* x  = (const float*)d_in[0];
    const int*   ei = (const int*)d_in[1];
    const float* ew = (const float*)d_in[2];
    const float* Wp[7];
    const float* Bp[7];
    for (int l = 0; l < 7; ++l) {
        Wp[l] = (const float*)d_in[3 + 2 * l];
        Bp[l] = (const float*)d_in[4 + 2 * l];
    }
    const int* row = ei;       // source
    const int* col = ei + NE;  // destination

    // workspace carve (~70 MB); Hb/Aa/Ab fp16, stride <= 64 halfs
    char* ws = (char*)d_ws;
    float* dinv  = (float*)ws;  ws += alignup((size_t)NN * 4);
    char*  Hb    = ws;          ws += alignup((size_t)NN * 64 * 2);
    char*  Aa    = ws;          ws += alignup((size_t)NN * 64 * 2);
    char*  Ab    = ws;          ws += alignup((size_t)NN * 64 * 2);
    int*   offs  = (int*)ws;    ws += alignup((size_t)(NN + 1) * 4);
    int*   counts= (int*)ws;    ws += alignup((size_t)NBUK * EB * 4);
    int*   btot  = (int*)ws;    ws += alignup((size_t)NBUK * 4);
    int*   bstart= (int*)ws;    ws += alignup((size_t)(NBUK + 1) * 4);
    int2*  stg   = (int2*)ws;   ws += alignup((size_t)NE * 8);
    int2*  csw   = (int2*)ws;   ws += alignup((size_t)NE * 8);

    const int gN = (NN + 255) / 256;

    // CSR build — no global atomics, no single-block O(N) scans
    k_hist0<<<EB, 256, 0, stream>>>(col, counts);
    k_scanA<<<NBUK, 256, 0, stream>>>(counts, btot);
    k_scanB<<<1, 256, 0, stream>>>(btot, bstart);
    k_A1<<<EB, 256, 0, stream>>>(row, col, ew, counts, bstart, stg);
    k_bdeg<<<NBUK, 256, 0, stream>>>(bstart, stg, dinv);
    k_place<<<NBUK, 512, 0, stream>>>(bstart, stg, dinv, offs, csw);

#define AGG(FOUT, S, LPN, RELU, OUT, LIDX)                                                  \
    k_agg2<FOUT, (S) / 2, S, LPN, RELU>                                                     \
        <<<((size_t)NN * (LPN) + 255) / 256, 256, 0, stream>>>(                             \
            offs, csw, (const __half2*)Hb, dinv, Bp[LIDX], (__half*)(OUT))

    // layer 1: fp32 x input; paired-chunk flattened grid (X HBM-read once)
    k_matmul_f<128, 50, 64, 2><<<gN * 2, 256, 0, stream>>>(x, Wp[0], (__half*)Hb);
    AGG(50, 64, 8, true, Aa, 0);
    // layers 2..6: fp16 activations in
    k_matmul_h<50, 64, 50, 64, 2><<<dim3(gN, 2), 256, 0, stream>>>((const __half*)Aa, Wp[1], (__half*)Hb);
    AGG(50, 64, 8, true, Ab, 1);
    k_matmul_h<50, 64, 30, 32, 2><<<dim3(gN, 2), 256, 0, stream>>>((const __half*)Ab, Wp[2], (__half*)Hb);
    AGG(30, 32, 4, true, Aa, 2);
    k_matmul_h<30, 32, 30, 32, 2><<<dim3(gN, 2), 256, 0, stream>>>((const __half*)Aa, Wp[3], (__half*)Hb);
    AGG(30, 32, 4, true, Ab, 3);
    k_matmul_h<30, 32, 10, 16, 1><<<dim3(gN, 1), 256, 0, stream>>>((const __half*)Ab, Wp[4], (__half*)Hb);
    AGG(10, 16, 2, true, Aa, 4);
    k_matmul_h<10, 16, 10, 16, 1><<<dim3(gN, 1), 256, 0, stream>>>((const __half*)Aa, Wp[5], (__half*)Hb);
    AGG(10, 16, 2, true, Ab, 5);
#undef AGG

    // layer 7: 10 -> 1, no relu, fp32 H, fp32 output
    k_matmul_1h<<<gN, 256, 0, stream>>>((const __half*)Ab, Wp[6], (float*)Hb);
    k_agg1<<<gN, 256, 0, stream>>>(offs, csw, (const float*)Hb, dinv, Bp[6],
                                   (float*)d_out);
}

// Round 6
// 479.873 us; speedup vs baseline: 2.3827x; 1.0055x over previous
//
#include <hip/hip_runtime.h>
#include <hip/hip_fp16.h>

// GCN, 7 layers: h = relu(Â (h W) + b), Â = D^-1/2 (A + I) D^-1/2.
// Round 21: layer-1 matmul -> bf16 split-precision MFMA GEMM.
//  Evidence: round-20 halved HBM bytes (99->55MB) but dur barely moved
//  (48->45us): the VALU GEMV is NOT byte-bound; it stalls on (a) W streamed
//  through s_load in <=112-SGPR chunks (serial lgkmcnt chain, K$ thrash),
//  (b) 64-distinct-lines-per-instruction X loads (TA tax). MFMA removes
//  both: operands broadcast in hardware, X staged coalesced into LDS.
//  Numerics: C = Xh*Wh + Xh*Wl + Xl*Wh (bf16 hi/lo residual split, fp32
//  acc) -> ~2^-18 relative error, far below the fp16 H-store rounding the
//  477us baseline already has; absmax should stay ~3e-5.
//  Layouts (cdna4 docs, m89-verified): C/D col=lane&15 row=(lane>>4)*4+reg;
//  A row=lane&15 k=(lane>>4)*8+j; B col=lane&15 same k. W staged transposed.
//  LDS 64KB exactly: 4 tiles [64][128] bf16, XOR-swizzle k^=((row&7)<<3)
//  on BOTH write and read -> conflict-free ds_read_b128 (G4).
//  All other kernels byte-identical to the 477-482us baseline.

static constexpr int NN = 100000;
static constexpr int NE = 1600000;
static constexpr int BKL = 9;                      // 512 nodes per bucket
static constexpr int NBUK = (NN + 511) >> BKL;     // 196 buckets
static constexpr int EPT = 8;                      // edges per thread (hist/A1)
static constexpr int EB = (NE + 2047) / 2048;      // 782 edge blocks

// ---------------- 1. bucket histogram (LDS only) ----------------

__global__ __launch_bounds__(256) void k_hist0(const int* __restrict__ col,
                                               int* __restrict__ counts) {
    __shared__ int lh[NBUK];
    for (int j = threadIdx.x; j < NBUK; j += 256) lh[j] = 0;
    __syncthreads();
    int base = blockIdx.x * 2048;
#pragma unroll
    for (int k = 0; k < EPT; ++k) {
        int e = base + k * 256 + threadIdx.x;
        if (e < NE) atomicAdd(&lh[col[e] >> BKL], 1);
    }
    __syncthreads();
    for (int j = threadIdx.x; j < NBUK; j += 256)
        counts[j * EB + blockIdx.x] = lh[j];  // bucket-major
}

// ---------------- 2a. per-bucket scan (196 parallel blocks) ----------------

__global__ __launch_bounds__(256) void k_scanA(int* __restrict__ counts,
                                               int* __restrict__ btot) {
    __shared__ int lds[256];
    const int b = blockIdx.x;
    const int t = threadIdx.x;
    int* c = counts + (size_t)b * EB;
    constexpr int PER = (EB + 255) / 256;  // 4
    int v[PER];
    int s = 0;
#pragma unroll
    for (int k = 0; k < PER; ++k) {
        int idx = t * PER + k;
        v[k] = (idx < EB) ? c[idx] : 0;
        s += v[k];
    }
    lds[t] = s;
    __syncthreads();
    for (int off = 1; off < 256; off <<= 1) {
        int u = (t >= off) ? lds[t - off] : 0;
        __syncthreads();
        lds[t] += u;
        __syncthreads();
    }
    int run = lds[t] - s;
#pragma unroll
    for (int k = 0; k < PER; ++k) {
        int idx = t * PER + k;
        if (idx < EB) { c[idx] = run; run += v[k]; }
    }
    if (t == 255) btot[b] = lds[255];
}

// ---------------- 2b. scan of 196 bucket totals -> bstart ----------------

__global__ void k_scanB(const int* __restrict__ btot, int* __restrict__ bstart) {
    __shared__ int lds[256];
    int t = threadIdx.x;
    int v = (t < NBUK) ? btot[t] : 0;
    lds[t] = v;
    __syncthreads();
    for (int off = 1; off < 256; off <<= 1) {
        int u = (t >= off) ? lds[t - off] : 0;
        __syncthreads();
        lds[t] += u;
        __syncthreads();
    }
    if (t < NBUK) bstart[t] = lds[t] - v;  // exclusive
    if (t == 0) bstart[NBUK] = NE;
}

// ---------------- 3. stage records, bucket-grouped (LDS cursors) ----------

__global__ __launch_bounds__(256) void k_A1(const int* __restrict__ row,
                                            const int* __restrict__ col,
                                            const float* __restrict__ ew,
                                            const int* __restrict__ counts,
                                            const int* __restrict__ bstart,
                                            int2* __restrict__ stg) {
    __shared__ int cur[NBUK];
    for (int j = threadIdx.x; j < NBUK; j += 256)
        cur[j] = bstart[j] + counts[j * EB + blockIdx.x];
    __syncthreads();
    int base = blockIdx.x * 2048;
#pragma unroll
    for (int k = 0; k < EPT; ++k) {
        int e = base + k * 256 + threadIdx.x;
        if (e < NE) {
            int c = col[e], r = row[e];
            int pos = atomicAdd(&cur[c >> BKL], 1);  // LDS atomic
            stg[pos] = make_int2(((c & 511) << 17) | r, __float_as_int(ew[e]));
        }
    }
}

// ---------------- 4. per-bucket degree -> dinv (plain stores) ----------

__global__ __launch_bounds__(256) void k_bdeg(const int* __restrict__ bstart,
                                              const int2* __restrict__ stg,
                                              float* __restrict__ dinv) {
    __shared__ float sdeg[512];
    const int b = blockIdx.x;
    for (int j = threadIdx.x; j < 512; j += 256) sdeg[j] = 0.0f;
    __syncthreads();
    const int s = bstart[b], e = bstart[b + 1];
    for (int p = s + threadIdx.x; p < e; p += 256) {
        int2 rec = stg[p];
        atomicAdd(&sdeg[rec.x >> 17], __int_as_float(rec.y));
    }
    __syncthreads();
    for (int j = threadIdx.x; j < 512; j += 256) {
        int idx = (b << BKL) + j;
        if (idx < NN) dinv[idx] = rsqrtf(sdeg[j] + 1.0f);  // +1 self-loop
    }
}

// ---------------- 5. per-bucket placement: offs + csw (LDS scan) ----------

__global__ __launch_bounds__(512) void k_place(const int* __restrict__ bstart,
                                               const int2* __restrict__ stg,
                                               const float* __restrict__ dinv,
                                               int* __restrict__ offs,
                                               int2* __restrict__ csw) {
    __shared__ int lcnt[512];
    __shared__ int cur[512];
    const int b = blockIdx.x;
    const int t = threadIdx.x;
    lcnt[t] = 0;
    __syncthreads();
    const int s = bstart[b], e = bstart[b + 1];
    for (int p = s + t; p < e; p += 512)
        atomicAdd(&lcnt[stg[p].x >> 17], 1);
    __syncthreads();
    int v = lcnt[t];
    for (int off = 1; off < 512; off <<= 1) {   // inclusive Hillis-Steele
        int u = (t >= off) ? lcnt[t - off] : 0;
        __syncthreads();
        lcnt[t] += u;
        __syncthreads();
    }
    int excl = lcnt[t] - v;
    int idx = (b << BKL) + t;
    if (idx <= NN) offs[idx] = s + excl;        // covers offs[NN] exactly once
    cur[t] = s + excl;
    __syncthreads();
    for (int p = s + t; p < e; p += 512) {
        int2 rec = stg[p];
        int cl = rec.x >> 17;
        int r = rec.x & 0x1FFFF;
        float nw = dinv[r] * __int_as_float(rec.y) * dinv[(b << BKL) + cl];
        int slot = atomicAdd(&cur[cl], 1);      // LDS atomic
        csw[slot] = make_int2(r, __float_as_int(nw));
    }
}

// ---------------- dense H = X * W, fp32 X (layer 1): bf16 split MFMA ------

typedef short s16x8 __attribute__((ext_vector_type(8)));
typedef short s16x4 __attribute__((ext_vector_type(4)));
typedef short s16x2 __attribute__((ext_vector_type(2)));
typedef float f32x4v __attribute__((ext_vector_type(4)));

static __device__ __forceinline__ unsigned short bf16rn(float f) {
    unsigned u = __float_as_uint(f);
    return (unsigned short)((u + 0x7FFFu + ((u >> 16) & 1u)) >> 16);
}

// half-index XOR swizzle within a 128-half row: conflict-free b128 reads
#define SWZ(r, k) ((k) ^ (((r) & 7) << 3))

__global__ __launch_bounds__(256) void k_matmul_f(const float* __restrict__ X,
                                                  const float* __restrict__ W,
                                                  __half* __restrict__ H) {
    __shared__ short lds[4 * 64 * 128];           // XH | XL | WHt | WLt = 64 KB
    constexpr int XH = 0, XL = 8192, WHo = 16384, WLo = 24576;
    const int t = threadIdx.x;
    const int blk = blockIdx.x;

    // ---- stage X tile: 64 rows x 128 f32 (coalesced), split hi/lo bf16 ----
    {
        const int g = t & 31;                     // float4 granule in row
        const int rs = t >> 5;                    // 0..7
#pragma unroll
        for (int i = 0; i < 8; ++i) {
            const int r = rs + 8 * i;
            const int row = blk * 64 + r;
            float4 v = make_float4(0.f, 0.f, 0.f, 0.f);
            if (row < NN) v = *(const float4*)(X + (size_t)row * 128 + g * 4);
            const float* vf = (const float*)&v;
            short h[4], l[4];
#pragma unroll
            for (int e = 0; e < 4; ++e) {
                unsigned short hb = bf16rn(vf[e]);
                float hf = __uint_as_float((unsigned)hb << 16);
                h[e] = (short)hb;
                l[e] = (short)bf16rn(vf[e] - hf);
            }
            const int k0 = SWZ(r, 4 * g);         // 4-half block stays intact
            *(s16x4*)&lds[XH + r * 128 + k0] = *(const s16x4*)h;
            *(s16x4*)&lds[XL + r * 128 + k0] = *(const s16x4*)l;
        }
    }
    // ---- stage W transposed: Wt[c][k], cols>=50 zero-padded ----
    {
        const int c = t & 63;
        const int kq = t >> 6;                    // 0..3
#pragma unroll
        for (int i = 0; i < 32; i += 2) {
            const int k = kq * 32 + i;
            float w0 = 0.f, w1 = 0.f;
            if (c < 50) { w0 = W[k * 50 + c]; w1 = W[(k + 1) * 50 + c]; }
            unsigned short h0 = bf16rn(w0), h1 = bf16rn(w1);
            float f0 = __uint_as_float((unsigned)h0 << 16);
            float f1 = __uint_as_float((unsigned)h1 << 16);
            short hh[2] = {(short)h0, (short)h1};
            short ll[2] = {(short)bf16rn(w0 - f0), (short)bf16rn(w1 - f1)};
            const int k0 = SWZ(c, k);             // k even: pair stays adjacent
            *(s16x2*)&lds[WHo + c * 128 + k0] = *(const s16x2*)hh;
            *(s16x2*)&lds[WLo + c * 128 + k0] = *(const s16x2*)ll;
        }
    }
    __syncthreads();

    // ---- compute: wave w owns rows [16w,16w+16); 4 col-tiles of 16 ----
    const int w = t >> 6;
    const int lane = t & 63;
    const int lr = lane & 15;                     // A row / B col within tile
    const int kg = lane >> 4;                     // k-group 0..3
    const int ar = 16 * w + lr;                   // A row in X tile
    f32x4v acc[4];
#pragma unroll
    for (int ct = 0; ct < 4; ++ct) acc[ct] = (f32x4v){0.f, 0.f, 0.f, 0.f};

#pragma unroll
    for (int kb = 0; kb < 4; ++kb) {
        const int kf = kb * 32 + kg * 8;          // lane's 8-half k-frag base
        const int ka = SWZ(ar, kf);
        s16x8 ah = *(const s16x8*)&lds[XH + ar * 128 + ka];
        s16x8 al = *(const s16x8*)&lds[XL + ar * 128 + ka];
        s16x8 bh[4], bl[4];
#pragma unroll
        for (int ct = 0; ct < 4; ++ct) {
            const int bc = ct * 16 + lr;
            const int kbo = SWZ(bc, kf);
            bh[ct] = *(const s16x8*)&lds[WHo + bc * 128 + kbo];
            bl[ct] = *(const s16x8*)&lds[WLo + bc * 128 + kbo];
        }
#pragma unroll
        for (int ct = 0; ct < 4; ++ct)
            acc[ct] = __builtin_amdgcn_mfma_f32_16x16x32_bf16(ah, bh[ct], acc[ct], 0, 0, 0);
#pragma unroll
        for (int ct = 0; ct < 4; ++ct)
            acc[ct] = __builtin_amdgcn_mfma_f32_16x16x32_bf16(ah, bl[ct], acc[ct], 0, 0, 0);
#pragma unroll
        for (int ct = 0; ct < 4; ++ct)
            acc[ct] = __builtin_amdgcn_mfma_f32_16x16x32_bf16(al, bh[ct], acc[ct], 0, 0, 0);
    }

    // ---- epilogue: C/D row = 16w + kg*4 + reg, col = 16ct + lr ----
    const int gr = blk * 64 + 16 * w + kg * 4;
#pragma unroll
    for (int ct = 0; ct < 4; ++ct) {
        const int col = ct * 16 + lr;
        if (col < 50) {
#pragma unroll
            for (int rg = 0; rg < 4; ++rg) {
                const int row = gr + rg;
                if (row < NN)
                    H[(size_t)row * 64 + col] = __float2half_rn(acc[ct][rg]);
            }
        }
    }
}
#undef SWZ

// ---------------- dense H = X * W, fp16 X (layers 2..6) ----------------
// All chunk loads issued upfront (<=7 independent int4s in flight), then
// pure FMA. Pad halfs beyond FIN are loaded but never used (bounded kk).

template <int FIN, int SX, int FOUT, int S, int NSPL>
__global__ __launch_bounds__(256, 2) void k_matmul_h(const __half* __restrict__ X,
                                                     const float* __restrict__ W,
                                                     __half* __restrict__ H) {
    constexpr int FC = FOUT / NSPL;
    constexpr int NCH = (FIN + 7) / 8;
    const int node = blockIdx.x * 256 + threadIdx.x;
    const int ch = blockIdx.y;                 // SGPR by construction
    if (node >= NN) return;
    const __half* xr = X + (size_t)node * SX;
    int4 raw[NCH];
#pragma unroll
    for (int c = 0; c < NCH; ++c) raw[c] = *(const int4*)(xr + 8 * c);
    float acc[FC];
#pragma unroll
    for (int j = 0; j < FC; ++j) acc[j] = 0.0f;
#pragma unroll
    for (int c = 0; c < NCH; ++c) {
        const __half2* hp = (const __half2*)&raw[c];
        const int lim = (FIN - 8 * c < 8) ? FIN - 8 * c : 8;  // folds post-unroll
#pragma unroll
        for (int kk = 0; kk < 8; ++kk) {
            if (kk < lim) {
                __half2 pair = hp[kk >> 1];
                float xv = (kk & 1) ? __high2float(pair) : __low2float(pair);
                const float* wrow = W + (8 * c + kk) * FOUT + ch * FC;
#pragma unroll
                for (int j = 0; j < FC; ++j) acc[j] = fmaf(xv, wrow[j], acc[j]);
            }
        }
    }
    __half* hr = H + (size_t)node * S + ch * FC;
#pragma unroll
    for (int j = 0; j < FC; ++j) hr[j] = __float2half_rn(acc[j]);
}

// layer 7: 10 -> 1, fp16 X (stride 16), fp32 H out
__global__ void k_matmul_1h(const __half* __restrict__ X, const float* __restrict__ W,
                            float* __restrict__ H) {
    int i = blockIdx.x * blockDim.x + threadIdx.x;
    if (i >= NN) return;
    const __half* xr = X + (size_t)i * 16;
    int4 r0 = *(const int4*)xr;                  // halfs 0..7
    __half2 r1 = *(const __half2*)(xr + 8);      // halfs 8,9
    const __half2* hp = (const __half2*)&r0;
    float acc = 0.0f;
#pragma unroll
    for (int q = 0; q < 4; ++q) {
        acc = fmaf(__low2float(hp[q]), W[2 * q], acc);
        acc = fmaf(__high2float(hp[q]), W[2 * q + 1], acc);
    }
    acc = fmaf(__low2float(r1), W[8], acc);
    acc = fmaf(__high2float(r1), W[9], acc);
    H[i] = acc;
}

// ---------------- CSR pull aggregation + fused epilogue (fp16 H) ----------
// Lane handles 4 half2s (one 16B gather per edge). Output stored fp16 at
// stride SA halfs (the next layer's X). csw records read nontemporal.

static __device__ __forceinline__ int2 nt_load2(const int2* p) {
    unsigned long long raw = __builtin_nontemporal_load((const unsigned long long*)p);
    return make_int2((int)(raw & 0xFFFFFFFFull), (int)(raw >> 32));
}

template <int F, int SH, int SA, int LPN, bool RELU>
__global__ __launch_bounds__(256) void k_agg2(const int* __restrict__ offs,
                                              const int2* __restrict__ csw,
                                              const __half2* __restrict__ H,
                                              const float* __restrict__ dinv,
                                              const float* __restrict__ b,
                                              __half* __restrict__ O) {
    constexpr int R = F / 2;               // real half2 count per row
    int t = blockIdx.x * blockDim.x + threadIdx.x;
    int g = t / LPN;
    int f = t - g * LPN;
    if (g >= NN) return;
    const int q0 = 4 * f;                  // first half2 this lane owns
    if (q0 >= R) return;                   // fully-pad lane: idle
    int p = offs[g];
    const int pe = offs[g + 1];
    const int pl = pe - 1;

    float2 acc[4];
#pragma unroll
    for (int c = 0; c < 4; ++c) acc[c] = make_float2(0.f, 0.f);

    for (; p < pe; p += 4) {
        int2 e[4];
#pragma unroll
        for (int i = 0; i < 4; ++i) e[i] = nt_load2(csw + min(p + i, pl));
        __half2 h[4][4];
#pragma unroll
        for (int i = 0; i < 4; ++i)
            *(int4*)h[i] = *(const int4*)(H + (size_t)e[i].x * SH + q0);
#pragma unroll
        for (int i = 0; i < 4; ++i) {
            float w = (p + i < pe) ? __int_as_float(e[i].y) : 0.0f;
#pragma unroll
            for (int c = 0; c < 4; ++c) {
                acc[c].x = fmaf(__low2float(h[i][c]), w, acc[c].x);
                acc[c].y = fmaf(__high2float(h[i][c]), w, acc[c].y);
            }
        }
    }

    float di = dinv[g];
    float d2 = di * di;
    __half2 hs[4];
    *(int4*)hs = *(const int4*)(H + (size_t)g * SH + q0);
    __half2* orow = (__half2*)(O + (size_t)g * SA) + q0;
#pragma unroll
    for (int c = 0; c < 4; ++c) {
        if (q0 + c < R) {
            float vx = acc[c].x + fmaf(__low2float(hs[c]), d2, b[2 * (q0 + c)]);
            float vy = acc[c].y + fmaf(__high2float(hs[c]), d2, b[2 * (q0 + c) + 1]);
            if (RELU) { vx = fmaxf(vx, 0.f); vy = fmaxf(vy, 0.f); }
            orow[c] = __floats2half2_rn(vx, vy);
        }
    }
}

// F=1 aggregation (final layer, fp32 H): one thread per node, predicated 4-wide.
__global__ void k_agg1(const int* __restrict__ offs, const int2* __restrict__ csw,
                       const float* __restrict__ H, const float* __restrict__ dinv,
                       const float* __restrict__ b, float* __restrict__ O) {
    int g = blockIdx.x * blockDim.x + threadIdx.x;
    if (g >= NN) return;
    int p = offs[g];
    const int pe = offs[g + 1];
    const int pl = pe - 1;
    float a0 = 0.f, a1 = 0.f, a2 = 0.f, a3 = 0.f;
    for (; p < pe; p += 4) {
        int2 e0 = nt_load2(csw + min(p, pl)),     e1 = nt_load2(csw + min(p + 1, pl));
        int2 e2 = nt_load2(csw + min(p + 2, pl)), e3 = nt_load2(csw + min(p + 3, pl));
        float w0 = (p < pe)     ? __int_as_float(e0.y) : 0.f;
        float w1 = (p + 1 < pe) ? __int_as_float(e1.y) : 0.f;
        float w2 = (p + 2 < pe) ? __int_as_float(e2.y) : 0.f;
        float w3 = (p + 3 < pe) ? __int_as_float(e3.y) : 0.f;
        a0 = fmaf(H[e0.x], w0, a0);
        a1 = fmaf(H[e1.x], w1, a1);
        a2 = fmaf(H[e2.x], w2, a2);
        a3 = fmaf(H[e3.x], w3, a3);
    }
    float di = dinv[g];
    O[g] = ((a0 + a1) + (a2 + a3)) + fmaf(H[g], di * di, b[0]);
}

// ---------------- launch ----------------

static inline size_t alignup(size_t x) { return (x + 255) & ~(size_t)255; }

extern "C" void kernel_launch(void* const* d_in, const int* in_sizes, int n_in,
                              void* d_out, int out_size, void* d_ws, size_t ws_size,
                              hipStream_t stream) {
    const float* x  = (const float*)d_in[0];
    const int*   ei = (const int*)d_in[1];
    const float* ew = (const float*)d_in[2];
    const float* Wp[7];
    const float* Bp[7];
    for (int l = 0; l < 7; ++l) {
        Wp[l] = (const float*)d_in[3 + 2 * l];
        Bp[l] = (const float*)d_in[4 + 2 * l];
    }
    const int* row = ei;       // source
    const int* col = ei + NE;  // destination

    // workspace carve (~70 MB); Hb/Aa/Ab fp16, stride <= 64 halfs
    char* ws = (char*)d_ws;
    float* dinv  = (float*)ws;  ws += alignup((size_t)NN * 4);
    char*  Hb    = ws;          ws += alignup((size_t)NN * 64 * 2);
    char*  Aa    = ws;          ws += alignup((size_t)NN * 64 * 2);
    char*  Ab    = ws;          ws += alignup((size_t)NN * 64 * 2);
    int*   offs  = (int*)ws;    ws += alignup((size_t)(NN + 1) * 4);
    int*   counts= (int*)ws;    ws += alignup((size_t)NBUK * EB * 4);
    int*   btot  = (int*)ws;    ws += alignup((size_t)NBUK * 4);
    int*   bstart= (int*)ws;    ws += alignup((size_t)(NBUK + 1) * 4);
    int2*  stg   = (int2*)ws;   ws += alignup((size_t)NE * 8);
    int2*  csw   = (int2*)ws;   ws += alignup((size_t)NE * 8);

    const int gN = (NN + 255) / 256;
    const int gM = (NN + 63) / 64;     // 64-row MFMA tiles

    // CSR build — no global atomics, no single-block O(N) scans
    k_hist0<<<EB, 256, 0, stream>>>(col, counts);
    k_scanA<<<NBUK, 256, 0, stream>>>(counts, btot);
    k_scanB<<<1, 256, 0, stream>>>(btot, bstart);
    k_A1<<<EB, 256, 0, stream>>>(row, col, ew, counts, bstart, stg);
    k_bdeg<<<NBUK, 256, 0, stream>>>(bstart, stg, dinv);
    k_place<<<NBUK, 512, 0, stream>>>(bstart, stg, dinv, offs, csw);

#define AGG(FOUT, S, LPN, RELU, OUT, LIDX)                                                  \
    k_agg2<FOUT, (S) / 2, S, LPN, RELU>                                                     \
        <<<((size_t)NN * (LPN) + 255) / 256, 256, 0, stream>>>(                             \
            offs, csw, (const __half2*)Hb, dinv, Bp[LIDX], (__half*)(OUT))

    // layer 1: fp32 x input, bf16 split-precision MFMA GEMM
    k_matmul_f<<<gM, 256, 0, stream>>>(x, Wp[0], (__half*)Hb);
    AGG(50, 64, 8, true, Aa, 0);
    // layers 2..6: fp16 activations in
    k_matmul_h<50, 64, 50, 64, 2><<<dim3(gN, 2), 256, 0, stream>>>((const __half*)Aa, Wp[1], (__half*)Hb);
    AGG(50, 64, 8, true, Ab, 1);
    k_matmul_h<50, 64, 30, 32, 2><<<dim3(gN, 2), 256, 0, stream>>>((const __half*)Ab, Wp[2], (__half*)Hb);
    AGG(30, 32, 4, true, Aa, 2);
    k_matmul_h<30, 32, 30, 32, 2><<<dim3(gN, 2), 256, 0, stream>>>((const __half*)Aa, Wp[3], (__half*)Hb);
    AGG(30, 32, 4, true, Ab, 3);
    k_matmul_h<30, 32, 10, 16, 1><<<dim3(gN, 1), 256, 0, stream>>>((const __half*)Ab, Wp[4], (__half*)Hb);
    AGG(10, 16, 2, true, Aa, 4);
    k_matmul_h<10, 16, 10, 16, 1><<<dim3(gN, 1), 256, 0, stream>>>((const __half*)Aa, Wp[5], (__half*)Hb);
    AGG(10, 16, 2, true, Ab, 5);
#undef AGG

    // layer 7: 10 -> 1, no relu, fp32 H, fp32 output
    k_matmul_1h<<<gN, 256, 0, stream>>>((const __half*)Ab, Wp[6], (float*)Hb);
    k_agg1<<<gN, 256, 0, stream>>>(offs, csw, (const float*)Hb, dinv, Bp[6],
                                   (float*)d_out);
}

// Round 7
// 457.723 us; speedup vs baseline: 2.4980x; 1.0484x over previous
//
#include <hip/hip_runtime.h>
#include <hip/hip_fp16.h>

// GCN, 7 layers: h = relu(Â (h W) + b), Â = D^-1/2 (A + I) D^-1/2.
// Round 22: MFMA layer-1 matmul, restructured from round-21 counters:
//  (a) 2.2M LDS bank conflicts == the W-staging writes (kq wave-uniform ->
//      8-way conflict on every write; 1408 cyc/block, matches counter).
//      Fix: W hi/lo split + transpose + swizzle PRECOMPUTED once by k_wsplit
//      (1 block) into workspace in final LDS layout; matmul stages it with a
//      linear conflict-free 32KB copy. Also removes ~640 conversion
//      VALU/thread that every block redid for the same 6400 floats.
//  (b) 64KB LDS -> 2 blocks/CU. Fix: no X tile at all — each lane loads its
//      A-fragment directly (32B contiguous/lane/kb; 16 fully-used lines per
//      wave-instr) and converts in regs (truncation split, ~5 VALU/elem).
//      LDS 32KB + launch_bounds(256,4) -> 4 blocks/CU.
//  MFMA layouts identical to round-21 (verified: absmax unchanged).
//  All other kernels byte-identical to the 477-482us baseline.

static constexpr int NN = 100000;
static constexpr int NE = 1600000;
static constexpr int BKL = 9;                      // 512 nodes per bucket
static constexpr int NBUK = (NN + 511) >> BKL;     // 196 buckets
static constexpr int EPT = 8;                      // edges per thread (hist/A1)
static constexpr int EB = (NE + 2047) / 2048;      // 782 edge blocks

// ---------------- 1. bucket histogram (LDS only) ----------------

__global__ __launch_bounds__(256) void k_hist0(const int* __restrict__ col,
                                               int* __restrict__ counts) {
    __shared__ int lh[NBUK];
    for (int j = threadIdx.x; j < NBUK; j += 256) lh[j] = 0;
    __syncthreads();
    int base = blockIdx.x * 2048;
#pragma unroll
    for (int k = 0; k < EPT; ++k) {
        int e = base + k * 256 + threadIdx.x;
        if (e < NE) atomicAdd(&lh[col[e] >> BKL], 1);
    }
    __syncthreads();
    for (int j = threadIdx.x; j < NBUK; j += 256)
        counts[j * EB + blockIdx.x] = lh[j];  // bucket-major
}

// ---------------- 2a. per-bucket scan (196 parallel blocks) ----------------

__global__ __launch_bounds__(256) void k_scanA(int* __restrict__ counts,
                                               int* __restrict__ btot) {
    __shared__ int lds[256];
    const int b = blockIdx.x;
    const int t = threadIdx.x;
    int* c = counts + (size_t)b * EB;
    constexpr int PER = (EB + 255) / 256;  // 4
    int v[PER];
    int s = 0;
#pragma unroll
    for (int k = 0; k < PER; ++k) {
        int idx = t * PER + k;
        v[k] = (idx < EB) ? c[idx] : 0;
        s += v[k];
    }
    lds[t] = s;
    __syncthreads();
    for (int off = 1; off < 256; off <<= 1) {
        int u = (t >= off) ? lds[t - off] : 0;
        __syncthreads();
        lds[t] += u;
        __syncthreads();
    }
    int run = lds[t] - s;
#pragma unroll
    for (int k = 0; k < PER; ++k) {
        int idx = t * PER + k;
        if (idx < EB) { c[idx] = run; run += v[k]; }
    }
    if (t == 255) btot[b] = lds[255];
}

// ---------------- 2b. scan of 196 bucket totals -> bstart ----------------

__global__ void k_scanB(const int* __restrict__ btot, int* __restrict__ bstart) {
    __shared__ int lds[256];
    int t = threadIdx.x;
    int v = (t < NBUK) ? btot[t] : 0;
    lds[t] = v;
    __syncthreads();
    for (int off = 1; off < 256; off <<= 1) {
        int u = (t >= off) ? lds[t - off] : 0;
        __syncthreads();
        lds[t] += u;
        __syncthreads();
    }
    if (t < NBUK) bstart[t] = lds[t] - v;  // exclusive
    if (t == 0) bstart[NBUK] = NE;
}

// ---------------- 3. stage records, bucket-grouped (LDS cursors) ----------

__global__ __launch_bounds__(256) void k_A1(const int* __restrict__ row,
                                            const int* __restrict__ col,
                                            const float* __restrict__ ew,
                                            const int* __restrict__ counts,
                                            const int* __restrict__ bstart,
                                            int2* __restrict__ stg) {
    __shared__ int cur[NBUK];
    for (int j = threadIdx.x; j < NBUK; j += 256)
        cur[j] = bstart[j] + counts[j * EB + blockIdx.x];
    __syncthreads();
    int base = blockIdx.x * 2048;
#pragma unroll
    for (int k = 0; k < EPT; ++k) {
        int e = base + k * 256 + threadIdx.x;
        if (e < NE) {
            int c = col[e], r = row[e];
            int pos = atomicAdd(&cur[c >> BKL], 1);  // LDS atomic
            stg[pos] = make_int2(((c & 511) << 17) | r, __float_as_int(ew[e]));
        }
    }
}

// ---------------- 4. per-bucket degree -> dinv (plain stores) ----------

__global__ __launch_bounds__(256) void k_bdeg(const int* __restrict__ bstart,
                                              const int2* __restrict__ stg,
                                              float* __restrict__ dinv) {
    __shared__ float sdeg[512];
    const int b = blockIdx.x;
    for (int j = threadIdx.x; j < 512; j += 256) sdeg[j] = 0.0f;
    __syncthreads();
    const int s = bstart[b], e = bstart[b + 1];
    for (int p = s + threadIdx.x; p < e; p += 256) {
        int2 rec = stg[p];
        atomicAdd(&sdeg[rec.x >> 17], __int_as_float(rec.y));
    }
    __syncthreads();
    for (int j = threadIdx.x; j < 512; j += 256) {
        int idx = (b << BKL) + j;
        if (idx < NN) dinv[idx] = rsqrtf(sdeg[j] + 1.0f);  // +1 self-loop
    }
}

// ---------------- 5. per-bucket placement: offs + csw (LDS scan) ----------

__global__ __launch_bounds__(512) void k_place(const int* __restrict__ bstart,
                                               const int2* __restrict__ stg,
                                               const float* __restrict__ dinv,
                                               int* __restrict__ offs,
                                               int2* __restrict__ csw) {
    __shared__ int lcnt[512];
    __shared__ int cur[512];
    const int b = blockIdx.x;
    const int t = threadIdx.x;
    lcnt[t] = 0;
    __syncthreads();
    const int s = bstart[b], e = bstart[b + 1];
    for (int p = s + t; p < e; p += 512)
        atomicAdd(&lcnt[stg[p].x >> 17], 1);
    __syncthreads();
    int v = lcnt[t];
    for (int off = 1; off < 512; off <<= 1) {   // inclusive Hillis-Steele
        int u = (t >= off) ? lcnt[t - off] : 0;
        __syncthreads();
        lcnt[t] += u;
        __syncthreads();
    }
    int excl = lcnt[t] - v;
    int idx = (b << BKL) + t;
    if (idx <= NN) offs[idx] = s + excl;        // covers offs[NN] exactly once
    cur[t] = s + excl;
    __syncthreads();
    for (int p = s + t; p < e; p += 512) {
        int2 rec = stg[p];
        int cl = rec.x >> 17;
        int r = rec.x & 0x1FFFF;
        float nw = dinv[r] * __int_as_float(rec.y) * dinv[(b << BKL) + cl];
        int slot = atomicAdd(&cur[cl], 1);      // LDS atomic
        csw[slot] = make_int2(r, __float_as_int(nw));
    }
}

// ---------------- dense H = X * W, fp32 X (layer 1): bf16 split MFMA ------

typedef short s16x8 __attribute__((ext_vector_type(8)));
typedef float f32x4v __attribute__((ext_vector_type(4)));

static __device__ __forceinline__ unsigned short bf16rn(float f) {
    unsigned u = __float_as_uint(f);
    return (unsigned short)((u + 0x7FFFu + ((u >> 16) & 1u)) >> 16);
}

// W pre-split: hi/lo bf16, transposed, XOR-swizzled into final LDS layout.
// wt[0..8191] = hi, wt[8192..16383] = lo; element (c,k) at c*128 + (k^((c&7)<<3)).
__global__ void k_wsplit(const float* __restrict__ W, short* __restrict__ wt) {
    const int t = threadIdx.x;
#pragma unroll
    for (int i = 0; i < 32; ++i) {
        const int li = t + 256 * i;            // 0..8191
        const int c = li >> 7, k = li & 127;
        float f = (c < 50) ? W[k * 50 + c] : 0.f;
        unsigned short hb = bf16rn(f);
        float hf = __uint_as_float((unsigned)hb << 16);
        unsigned short lb = bf16rn(f - hf);
        const int off = c * 128 + (k ^ ((c & 7) << 3));
        wt[off] = (short)hb;
        wt[8192 + off] = (short)lb;
    }
}

__global__ __launch_bounds__(256, 4) void k_matmul_f(const float* __restrict__ X,
                                                     const short* __restrict__ wt,
                                                     __half* __restrict__ H) {
    __shared__ short lds[2 * 64 * 128];           // Wt hi | lo, pre-swizzled, 32 KB
    const int t = threadIdx.x;

    // stage W: linear 32KB copy, 16B/lane coalesced, conflict-free writes
    {
        const int4* src = (const int4*)wt;
        int4* dst = (int4*)lds;
#pragma unroll
        for (int j = 0; j < 8; ++j) dst[j * 256 + t] = src[j * 256 + t];
    }

    const int w = t >> 6;
    const int lane = t & 63;
    const int lr = lane & 15;                     // A row / B col within tile
    const int kg = lane >> 4;                     // k-group 0..3
    const int row = blockIdx.x * 64 + 16 * w + lr;
    const float* xr = X + (size_t)(row < NN ? row : NN - 1) * 128 + kg * 8;

    // issue all 8 X loads upfront (independent; overlap the barrier wait)
    float4 xa[4][2];
#pragma unroll
    for (int kb = 0; kb < 4; ++kb) {
        xa[kb][0] = *(const float4*)(xr + kb * 32);
        xa[kb][1] = *(const float4*)(xr + kb * 32 + 4);
    }

    __syncthreads();

    f32x4v acc[4];
#pragma unroll
    for (int ct = 0; ct < 4; ++ct) acc[ct] = (f32x4v){0.f, 0.f, 0.f, 0.f};

#pragma unroll
    for (int kb = 0; kb < 4; ++kb) {
        // in-reg truncation split: hi = top 16 bits, lo = bf16(f - hi)
        s16x8 ah, al;
        const unsigned* xu = (const unsigned*)&xa[kb][0];
#pragma unroll
        for (int e = 0; e < 8; ++e) {
            const unsigned u = xu[e];
            const float lo = __uint_as_float(u) - __uint_as_float(u & 0xFFFF0000u);
            ah[e] = (short)(u >> 16);
            al[e] = (short)(__float_as_uint(lo) >> 16);
        }
        const int kf = kb * 32 + kg * 8;
        s16x8 bh[4], bl[4];
#pragma unroll
        for (int ct = 0; ct < 4; ++ct) {
            const int bc = ct * 16 + lr;
            const int ko = bc * 128 + (kf ^ ((bc & 7) << 3));
            bh[ct] = *(const s16x8*)&lds[ko];
            bl[ct] = *(const s16x8*)&lds[8192 + ko];
        }
#pragma unroll
        for (int ct = 0; ct < 4; ++ct)
            acc[ct] = __builtin_amdgcn_mfma_f32_16x16x32_bf16(ah, bh[ct], acc[ct], 0, 0, 0);
#pragma unroll
        for (int ct = 0; ct < 4; ++ct)
            acc[ct] = __builtin_amdgcn_mfma_f32_16x16x32_bf16(ah, bl[ct], acc[ct], 0, 0, 0);
#pragma unroll
        for (int ct = 0; ct < 4; ++ct)
            acc[ct] = __builtin_amdgcn_mfma_f32_16x16x32_bf16(al, bh[ct], acc[ct], 0, 0, 0);
    }

    // epilogue: C/D row = 16w + kg*4 + reg, col = 16ct + lr
    const int gr = blockIdx.x * 64 + 16 * w + kg * 4;
#pragma unroll
    for (int ct = 0; ct < 4; ++ct) {
        const int col = ct * 16 + lr;
        if (col < 50) {
#pragma unroll
            for (int rg = 0; rg < 4; ++rg) {
                const int orow = gr + rg;
                if (orow < NN)
                    H[(size_t)orow * 64 + col] = __float2half_rn(acc[ct][rg]);
            }
        }
    }
}

// ---------------- dense H = X * W, fp16 X (layers 2..6) ----------------
// All chunk loads issued upfront (<=7 independent int4s in flight), then
// pure FMA. Pad halfs beyond FIN are loaded but never used (bounded kk).

template <int FIN, int SX, int FOUT, int S, int NSPL>
__global__ __launch_bounds__(256, 2) void k_matmul_h(const __half* __restrict__ X,
                                                     const float* __restrict__ W,
                                                     __half* __restrict__ H) {
    constexpr int FC = FOUT / NSPL;
    constexpr int NCH = (FIN + 7) / 8;
    const int node = blockIdx.x * 256 + threadIdx.x;
    const int ch = blockIdx.y;                 // SGPR by construction
    if (node >= NN) return;
    const __half* xr = X + (size_t)node * SX;
    int4 raw[NCH];
#pragma unroll
    for (int c = 0; c < NCH; ++c) raw[c] = *(const int4*)(xr + 8 * c);
    float acc[FC];
#pragma unroll
    for (int j = 0; j < FC; ++j) acc[j] = 0.0f;
#pragma unroll
    for (int c = 0; c < NCH; ++c) {
        const __half2* hp = (const __half2*)&raw[c];
        const int lim = (FIN - 8 * c < 8) ? FIN - 8 * c : 8;  // folds post-unroll
#pragma unroll
        for (int kk = 0; kk < 8; ++kk) {
            if (kk < lim) {
                __half2 pair = hp[kk >> 1];
                float xv = (kk & 1) ? __high2float(pair) : __low2float(pair);
                const float* wrow = W + (8 * c + kk) * FOUT + ch * FC;
#pragma unroll
                for (int j = 0; j < FC; ++j) acc[j] = fmaf(xv, wrow[j], acc[j]);
            }
        }
    }
    __half* hr = H + (size_t)node * S + ch * FC;
#pragma unroll
    for (int j = 0; j < FC; ++j) hr[j] = __float2half_rn(acc[j]);
}

// layer 7: 10 -> 1, fp16 X (stride 16), fp32 H out
__global__ void k_matmul_1h(const __half* __restrict__ X, const float* __restrict__ W,
                            float* __restrict__ H) {
    int i = blockIdx.x * blockDim.x + threadIdx.x;
    if (i >= NN) return;
    const __half* xr = X + (size_t)i * 16;
    int4 r0 = *(const int4*)xr;                  // halfs 0..7
    __half2 r1 = *(const __half2*)(xr + 8);      // halfs 8,9
    const __half2* hp = (const __half2*)&r0;
    float acc = 0.0f;
#pragma unroll
    for (int q = 0; q < 4; ++q) {
        acc = fmaf(__low2float(hp[q]), W[2 * q], acc);
        acc = fmaf(__high2float(hp[q]), W[2 * q + 1], acc);
    }
    acc = fmaf(__low2float(r1), W[8], acc);
    acc = fmaf(__high2float(r1), W[9], acc);
    H[i] = acc;
}

// ---------------- CSR pull aggregation + fused epilogue (fp16 H) ----------
// Lane handles 4 half2s (one 16B gather per edge). Output stored fp16 at
// stride SA halfs (the next layer's X). csw records read nontemporal.

static __device__ __forceinline__ int2 nt_load2(const int2* p) {
    unsigned long long raw = __builtin_nontemporal_load((const unsigned long long*)p);
    return make_int2((int)(raw & 0xFFFFFFFFull), (int)(raw >> 32));
}

template <int F, int SH, int SA, int LPN, bool RELU>
__global__ __launch_bounds__(256) void k_agg2(const int* __restrict__ offs,
                                              const int2* __restrict__ csw,
                                              const __half2* __restrict__ H,
                                              const float* __restrict__ dinv,
                                              const float* __restrict__ b,
                                              __half* __restrict__ O) {
    constexpr int R = F / 2;               // real half2 count per row
    int t = blockIdx.x * blockDim.x + threadIdx.x;
    int g = t / LPN;
    int f = t - g * LPN;
    if (g >= NN) return;
    const int q0 = 4 * f;                  // first half2 this lane owns
    if (q0 >= R) return;                   // fully-pad lane: idle
    int p = offs[g];
    const int pe = offs[g + 1];
    const int pl = pe - 1;

    float2 acc[4];
#pragma unroll
    for (int c = 0; c < 4; ++c) acc[c] = make_float2(0.f, 0.f);

    for (; p < pe; p += 4) {
        int2 e[4];
#pragma unroll
        for (int i = 0; i < 4; ++i) e[i] = nt_load2(csw + min(p + i, pl));
        __half2 h[4][4];
#pragma unroll
        for (int i = 0; i < 4; ++i)
            *(int4*)h[i] = *(const int4*)(H + (size_t)e[i].x * SH + q0);
#pragma unroll
        for (int i = 0; i < 4; ++i) {
            float w = (p + i < pe) ? __int_as_float(e[i].y) : 0.0f;
#pragma unroll
            for (int c = 0; c < 4; ++c) {
                acc[c].x = fmaf(__low2float(h[i][c]), w, acc[c].x);
                acc[c].y = fmaf(__high2float(h[i][c]), w, acc[c].y);
            }
        }
    }

    float di = dinv[g];
    float d2 = di * di;
    __half2 hs[4];
    *(int4*)hs = *(const int4*)(H + (size_t)g * SH + q0);
    __half2* orow = (__half2*)(O + (size_t)g * SA) + q0;
#pragma unroll
    for (int c = 0; c < 4; ++c) {
        if (q0 + c < R) {
            float vx = acc[c].x + fmaf(__low2float(hs[c]), d2, b[2 * (q0 + c)]);
            float vy = acc[c].y + fmaf(__high2float(hs[c]), d2, b[2 * (q0 + c) + 1]);
            if (RELU) { vx = fmaxf(vx, 0.f); vy = fmaxf(vy, 0.f); }
            orow[c] = __floats2half2_rn(vx, vy);
        }
    }
}

// F=1 aggregation (final layer, fp32 H): one thread per node, predicated 4-wide.
__global__ void k_agg1(const int* __restrict__ offs, const int2* __restrict__ csw,
                       const float* __restrict__ H, const float* __restrict__ dinv,
                       const float* __restrict__ b, float* __restrict__ O) {
    int g = blockIdx.x * blockDim.x + threadIdx.x;
    if (g >= NN) return;
    int p = offs[g];
    const int pe = offs[g + 1];
    const int pl = pe - 1;
    float a0 = 0.f, a1 = 0.f, a2 = 0.f, a3 = 0.f;
    for (; p < pe; p += 4) {
        int2 e0 = nt_load2(csw + min(p, pl)),     e1 = nt_load2(csw + min(p + 1, pl));
        int2 e2 = nt_load2(csw + min(p + 2, pl)), e3 = nt_load2(csw + min(p + 3, pl));
        float w0 = (p < pe)     ? __int_as_float(e0.y) : 0.f;
        float w1 = (p + 1 < pe) ? __int_as_float(e1.y) : 0.f;
        float w2 = (p + 2 < pe) ? __int_as_float(e2.y) : 0.f;
        float w3 = (p + 3 < pe) ? __int_as_float(e3.y) : 0.f;
        a0 = fmaf(H[e0.x], w0, a0);
        a1 = fmaf(H[e1.x], w1, a1);
        a2 = fmaf(H[e2.x], w2, a2);
        a3 = fmaf(H[e3.x], w3, a3);
    }
    float di = dinv[g];
    O[g] = ((a0 + a1) + (a2 + a3)) + fmaf(H[g], di * di, b[0]);
}

// ---------------- launch ----------------

static inline size_t alignup(size_t x) { return (x + 255) & ~(size_t)255; }

extern "C" void kernel_launch(void* const* d_in, const int* in_sizes, int n_in,
                              void* d_out, int out_size, void* d_ws, size_t ws_size,
                              hipStream_t stream) {
    const float* x  = (const float*)d_in[0];
    const int*   ei = (const int*)d_in[1];
    const float* ew = (const float*)d_in[2];
    const float* Wp[7];
    const float* Bp[7];
    for (int l = 0; l < 7; ++l) {
        Wp[l] = (const float*)d_in[3 + 2 * l];
        Bp[l] = (const float*)d_in[4 + 2 * l];
    }
    const int* row = ei;       // source
    const int* col = ei + NE;  // destination

    // workspace carve (~70 MB); Hb/Aa/Ab fp16, stride <= 64 halfs
    char* ws = (char*)d_ws;
    float* dinv  = (float*)ws;  ws += alignup((size_t)NN * 4);
    char*  Hb    = ws;          ws += alignup((size_t)NN * 64 * 2);
    char*  Aa    = ws;          ws += alignup((size_t)NN * 64 * 2);
    char*  Ab    = ws;          ws += alignup((size_t)NN * 64 * 2);
    int*   offs  = (int*)ws;    ws += alignup((size_t)(NN + 1) * 4);
    int*   counts= (int*)ws;    ws += alignup((size_t)NBUK * EB * 4);
    int*   btot  = (int*)ws;    ws += alignup((size_t)NBUK * 4);
    int*   bstart= (int*)ws;    ws += alignup((size_t)(NBUK + 1) * 4);
    int2*  stg   = (int2*)ws;   ws += alignup((size_t)NE * 8);
    int2*  csw   = (int2*)ws;   ws += alignup((size_t)NE * 8);
    short* wt    = (short*)ws;  ws += alignup((size_t)2 * 64 * 128 * 2);

    const int gN = (NN + 255) / 256;
    const int gM = (NN + 63) / 64;     // 64-row MFMA tiles

    // W pre-split (tiny) + CSR build — no global atomics, no 1-block O(N) scans
    k_wsplit<<<1, 256, 0, stream>>>(Wp[0], wt);
    k_hist0<<<EB, 256, 0, stream>>>(col, counts);
    k_scanA<<<NBUK, 256, 0, stream>>>(counts, btot);
    k_scanB<<<1, 256, 0, stream>>>(btot, bstart);
    k_A1<<<EB, 256, 0, stream>>>(row, col, ew, counts, bstart, stg);
    k_bdeg<<<NBUK, 256, 0, stream>>>(bstart, stg, dinv);
    k_place<<<NBUK, 512, 0, stream>>>(bstart, stg, dinv, offs, csw);

#define AGG(FOUT, S, LPN, RELU, OUT, LIDX)                                                  \
    k_agg2<FOUT, (S) / 2, S, LPN, RELU>                                                     \
        <<<((size_t)NN * (LPN) + 255) / 256, 256, 0, stream>>>(                             \
            offs, csw, (const __half2*)Hb, dinv, Bp[LIDX], (__half*)(OUT))

    // layer 1: fp32 x input, bf16 split MFMA (W pre-staged, X direct)
    k_matmul_f<<<gM, 256, 0, stream>>>(x, wt, (__half*)Hb);
    AGG(50, 64, 8, true, Aa, 0);
    // layers 2..6: fp16 activations in
    k_matmul_h<50, 64, 50, 64, 2><<<dim3(gN, 2), 256, 0, stream>>>((const __half*)Aa, Wp[1], (__half*)Hb);
    AGG(50, 64, 8, true, Ab, 1);
    k_matmul_h<50, 64, 30, 32, 2><<<dim3(gN, 2), 256, 0, stream>>>((const __half*)Ab, Wp[2], (__half*)Hb);
    AGG(30, 32, 4, true, Aa, 2);
    k_matmul_h<30, 32, 30, 32, 2><<<dim3(gN, 2), 256, 0, stream>>>((const __half*)Aa, Wp[3], (__half*)Hb);
    AGG(30, 32, 4, true, Ab, 3);
    k_matmul_h<30, 32, 10, 16, 1><<<dim3(gN, 1), 256, 0, stream>>>((const __half*)Ab, Wp[4], (__half*)Hb);
    AGG(10, 16, 2, true, Aa, 4);
    k_matmul_h<10, 16, 10, 16, 1><<<dim3(gN, 1), 256, 0, stream>>>((const __half*)Aa, Wp[5], (__half*)Hb);
    AGG(10, 16, 2, true, Ab, 5);
#undef AGG

    // layer 7: 10 -> 1, no relu, fp32 H, fp32 output
    k_matmul_1h<<<gN, 256, 0, stream>>>((const __half*)Ab, Wp[6], (float*)Hb);
    k_agg1<<<gN, 256, 0, stream>>>(offs, csw, (const float*)Hb, dinv, Bp[6],
                                   (float*)d_out);
}

// Round 8
// 442.044 us; speedup vs baseline: 2.5866x; 1.0355x over previous
//
#include <hip/hip_runtime.h>
#include <hip/hip_fp16.h>

// GCN, 7 layers: h = relu(Â (h W) + b), Â = D^-1/2 (A + I) D^-1/2.
// Round 23: extend the (twice-verified) MFMA matmul to layers 2-5.
//  Round-22 result: layer-1 MFMA + pre-split W + direct X frags = -22us
//  (479.9 -> 457.7, prediction matched; absmax unchanged -> layouts right).
//  Layers 2-5 (50->50, 50->30, 30->30, 30->10) still use the VALU GEMV with
//  the same two structural defects measured on layer 1 (W s_load chain,
//  1250 FMA/thread). Port: fp16 MFMA — activations are ALREADY fp16 in
//  A-fragment order (raw 16B load, zero conversion); W = Wh + Wl fp16 hi/lo
//  split (~22-bit W >= fp32-W accuracy here), prepped once by k_wprep:
//  transposed, zero-padded, odd-granule pitch (72/40 halfs -> bank phase
//  4c%32 / 20c%32, <=2-way = free) -> linear conflict-free LDS stage.
//  Prereq: MFMA reads K-pad halfs of X; workspace may be poison -> k_agg2
//  epilogue now zero-fills pad halfs of its output rows (same store count).
//  Layers 6-7 (10-wide) stay VALU. Layer-1 kernel untouched.

static constexpr int NN = 100000;
static constexpr int NE = 1600000;
static constexpr int BKL = 9;                      // 512 nodes per bucket
static constexpr int NBUK = (NN + 511) >> BKL;     // 196 buckets
static constexpr int EPT = 8;                      // edges per thread (hist/A1)
static constexpr int EB = (NE + 2047) / 2048;      // 782 edge blocks

// ---------------- 1. bucket histogram (LDS only) ----------------

__global__ __launch_bounds__(256) void k_hist0(const int* __restrict__ col,
                                               int* __restrict__ counts) {
    __shared__ int lh[NBUK];
    for (int j = threadIdx.x; j < NBUK; j += 256) lh[j] = 0;
    __syncthreads();
    int base = blockIdx.x * 2048;
#pragma unroll
    for (int k = 0; k < EPT; ++k) {
        int e = base + k * 256 + threadIdx.x;
        if (e < NE) atomicAdd(&lh[col[e] >> BKL], 1);
    }
    __syncthreads();
    for (int j = threadIdx.x; j < NBUK; j += 256)
        counts[j * EB + blockIdx.x] = lh[j];  // bucket-major
}

// ---------------- 2a. per-bucket scan (196 parallel blocks) ----------------

__global__ __launch_bounds__(256) void k_scanA(int* __restrict__ counts,
                                               int* __restrict__ btot) {
    __shared__ int lds[256];
    const int b = blockIdx.x;
    const int t = threadIdx.x;
    int* c = counts + (size_t)b * EB;
    constexpr int PER = (EB + 255) / 256;  // 4
    int v[PER];
    int s = 0;
#pragma unroll
    for (int k = 0; k < PER; ++k) {
        int idx = t * PER + k;
        v[k] = (idx < EB) ? c[idx] : 0;
        s += v[k];
    }
    lds[t] = s;
    __syncthreads();
    for (int off = 1; off < 256; off <<= 1) {
        int u = (t >= off) ? lds[t - off] : 0;
        __syncthreads();
        lds[t] += u;
        __syncthreads();
    }
    int run = lds[t] - s;
#pragma unroll
    for (int k = 0; k < PER; ++k) {
        int idx = t * PER + k;
        if (idx < EB) { c[idx] = run; run += v[k]; }
    }
    if (t == 255) btot[b] = lds[255];
}

// ---------------- 2b. scan of 196 bucket totals -> bstart ----------------

__global__ void k_scanB(const int* __restrict__ btot, int* __restrict__ bstart) {
    __shared__ int lds[256];
    int t = threadIdx.x;
    int v = (t < NBUK) ? btot[t] : 0;
    lds[t] = v;
    __syncthreads();
    for (int off = 1; off < 256; off <<= 1) {
        int u = (t >= off) ? lds[t - off] : 0;
        __syncthreads();
        lds[t] += u;
        __syncthreads();
    }
    if (t < NBUK) bstart[t] = lds[t] - v;  // exclusive
    if (t == 0) bstart[NBUK] = NE;
}

// ---------------- 3. stage records, bucket-grouped (LDS cursors) ----------

__global__ __launch_bounds__(256) void k_A1(const int* __restrict__ row,
                                            const int* __restrict__ col,
                                            const float* __restrict__ ew,
                                            const int* __restrict__ counts,
                                            const int* __restrict__ bstart,
                                            int2* __restrict__ stg) {
    __shared__ int cur[NBUK];
    for (int j = threadIdx.x; j < NBUK; j += 256)
        cur[j] = bstart[j] + counts[j * EB + blockIdx.x];
    __syncthreads();
    int base = blockIdx.x * 2048;
#pragma unroll
    for (int k = 0; k < EPT; ++k) {
        int e = base + k * 256 + threadIdx.x;
        if (e < NE) {
            int c = col[e], r = row[e];
            int pos = atomicAdd(&cur[c >> BKL], 1);  // LDS atomic
            stg[pos] = make_int2(((c & 511) << 17) | r, __float_as_int(ew[e]));
        }
    }
}

// ---------------- 4. per-bucket degree -> dinv (plain stores) ----------

__global__ __launch_bounds__(256) void k_bdeg(const int* __restrict__ bstart,
                                              const int2* __restrict__ stg,
                                              float* __restrict__ dinv) {
    __shared__ float sdeg[512];
    const int b = blockIdx.x;
    for (int j = threadIdx.x; j < 512; j += 256) sdeg[j] = 0.0f;
    __syncthreads();
    const int s = bstart[b], e = bstart[b + 1];
    for (int p = s + threadIdx.x; p < e; p += 256) {
        int2 rec = stg[p];
        atomicAdd(&sdeg[rec.x >> 17], __int_as_float(rec.y));
    }
    __syncthreads();
    for (int j = threadIdx.x; j < 512; j += 256) {
        int idx = (b << BKL) + j;
        if (idx < NN) dinv[idx] = rsqrtf(sdeg[j] + 1.0f);  // +1 self-loop
    }
}

// ---------------- 5. per-bucket placement: offs + csw (LDS scan) ----------

__global__ __launch_bounds__(512) void k_place(const int* __restrict__ bstart,
                                               const int2* __restrict__ stg,
                                               const float* __restrict__ dinv,
                                               int* __restrict__ offs,
                                               int2* __restrict__ csw) {
    __shared__ int lcnt[512];
    __shared__ int cur[512];
    const int b = blockIdx.x;
    const int t = threadIdx.x;
    lcnt[t] = 0;
    __syncthreads();
    const int s = bstart[b], e = bstart[b + 1];
    for (int p = s + t; p < e; p += 512)
        atomicAdd(&lcnt[stg[p].x >> 17], 1);
    __syncthreads();
    int v = lcnt[t];
    for (int off = 1; off < 512; off <<= 1) {   // inclusive Hillis-Steele
        int u = (t >= off) ? lcnt[t - off] : 0;
        __syncthreads();
        lcnt[t] += u;
        __syncthreads();
    }
    int excl = lcnt[t] - v;
    int idx = (b << BKL) + t;
    if (idx <= NN) offs[idx] = s + excl;        // covers offs[NN] exactly once
    cur[t] = s + excl;
    __syncthreads();
    for (int p = s + t; p < e; p += 512) {
        int2 rec = stg[p];
        int cl = rec.x >> 17;
        int r = rec.x & 0x1FFFF;
        float nw = dinv[r] * __int_as_float(rec.y) * dinv[(b << BKL) + cl];
        int slot = atomicAdd(&cur[cl], 1);      // LDS atomic
        csw[slot] = make_int2(r, __float_as_int(nw));
    }
}

// ---------------- weight prep (one tiny block, runs once per graph) -------

typedef short s16x8 __attribute__((ext_vector_type(8)));
typedef float f32x4v __attribute__((ext_vector_type(4)));
typedef _Float16 f16x8 __attribute__((ext_vector_type(8)));

static __device__ __forceinline__ unsigned short bf16rn(float f) {
    unsigned u = __float_as_uint(f);
    return (unsigned short)((u + 0x7FFFu + ((u >> 16) & 1u)) >> 16);
}

// wt layout (shorts):
//  [0, 16384)      layer-1 bf16 hi|lo, transposed, XOR-swizzled (round-22)
//  [WT2..) fp16 hi|lo transposed tiles, pitch-padded, for layers 2..5
static constexpr int WT2 = 16384;                  // 64c x 72p x2 = 9216
static constexpr int WT3 = WT2 + 9216;             // 32c x 72p x2 = 4608
static constexpr int WT4 = WT3 + 4608;             // 32c x 40p x2 = 2560
static constexpr int WT5 = WT4 + 2560;             // 16c x 40p x2 = 1280
static constexpr int WT_TOT = WT5 + 1280;

static __device__ __forceinline__ void prep_f16(const float* __restrict__ W,
                                                int FIN, int FOUT, int KP,
                                                int PITCH, int NCT,
                                                short* __restrict__ dst, int t) {
    const int WCNT = NCT * 16 * PITCH;
    for (int li = t; li < NCT * 16 * KP; li += 256) {
        const int c = li / KP, k = li - c * KP;
        float f = (c < FOUT && k < FIN) ? W[k * FOUT + c] : 0.f;
        __half hh = __float2half_rn(f);
        __half hl = __float2half_rn(f - __half2float(hh));
        dst[c * PITCH + k] = __half_as_short(hh);
        dst[WCNT + c * PITCH + k] = __half_as_short(hl);
    }
}

__global__ void k_wprep(const float* __restrict__ W0, const float* __restrict__ W1,
                        const float* __restrict__ W2, const float* __restrict__ W3,
                        const float* __restrict__ W4, short* __restrict__ wt) {
    const int t = threadIdx.x;
    // layer-1 bf16 split (unchanged layout)
#pragma unroll
    for (int i = 0; i < 32; ++i) {
        const int li = t + 256 * i;            // 0..8191
        const int c = li >> 7, k = li & 127;
        float f = (c < 50) ? W0[k * 50 + c] : 0.f;
        unsigned short hb = bf16rn(f);
        float hf = __uint_as_float((unsigned)hb << 16);
        unsigned short lb = bf16rn(f - hf);
        const int off = c * 128 + (k ^ ((c & 7) << 3));
        wt[off] = (short)hb;
        wt[8192 + off] = (short)lb;
    }
    prep_f16(W1, 50, 50, 64, 72, 4, wt + WT2, t);
    prep_f16(W2, 50, 30, 64, 72, 2, wt + WT3, t);
    prep_f16(W3, 30, 30, 32, 40, 2, wt + WT4, t);
    prep_f16(W4, 30, 10, 32, 40, 1, wt + WT5, t);
}

// ---------------- layer 1: fp32 X, bf16 split MFMA (round-22, verified) ---

__global__ __launch_bounds__(256, 4) void k_matmul_f(const float* __restrict__ X,
                                                     const short* __restrict__ wt,
                                                     __half* __restrict__ H) {
    __shared__ short lds[2 * 64 * 128];           // Wt hi | lo, pre-swizzled, 32 KB
    const int t = threadIdx.x;
    {
        const int4* src = (const int4*)wt;
        int4* dst = (int4*)lds;
#pragma unroll
        for (int j = 0; j < 8; ++j) dst[j * 256 + t] = src[j * 256 + t];
    }
    const int w = t >> 6;
    const int lane = t & 63;
    const int lr = lane & 15;
    const int kg = lane >> 4;
    const int row = blockIdx.x * 64 + 16 * w + lr;
    const float* xr = X + (size_t)(row < NN ? row : NN - 1) * 128 + kg * 8;

    float4 xa[4][2];
#pragma unroll
    for (int kb = 0; kb < 4; ++kb) {
        xa[kb][0] = *(const float4*)(xr + kb * 32);
        xa[kb][1] = *(const float4*)(xr + kb * 32 + 4);
    }
    __syncthreads();

    f32x4v acc[4];
#pragma unroll
    for (int ct = 0; ct < 4; ++ct) acc[ct] = (f32x4v){0.f, 0.f, 0.f, 0.f};

#pragma unroll
    for (int kb = 0; kb < 4; ++kb) {
        s16x8 ah, al;
        const unsigned* xu = (const unsigned*)&xa[kb][0];
#pragma unroll
        for (int e = 0; e < 8; ++e) {
            const unsigned u = xu[e];
            const float lo = __uint_as_float(u) - __uint_as_float(u & 0xFFFF0000u);
            ah[e] = (short)(u >> 16);
            al[e] = (short)(__float_as_uint(lo) >> 16);
        }
        const int kf = kb * 32 + kg * 8;
        s16x8 bh[4], bl[4];
#pragma unroll
        for (int ct = 0; ct < 4; ++ct) {
            const int bc = ct * 16 + lr;
            const int ko = bc * 128 + (kf ^ ((bc & 7) << 3));
            bh[ct] = *(const s16x8*)&lds[ko];
            bl[ct] = *(const s16x8*)&lds[8192 + ko];
        }
#pragma unroll
        for (int ct = 0; ct < 4; ++ct)
            acc[ct] = __builtin_amdgcn_mfma_f32_16x16x32_bf16(ah, bh[ct], acc[ct], 0, 0, 0);
#pragma unroll
        for (int ct = 0; ct < 4; ++ct)
            acc[ct] = __builtin_amdgcn_mfma_f32_16x16x32_bf16(ah, bl[ct], acc[ct], 0, 0, 0);
#pragma unroll
        for (int ct = 0; ct < 4; ++ct)
            acc[ct] = __builtin_amdgcn_mfma_f32_16x16x32_bf16(al, bh[ct], acc[ct], 0, 0, 0);
    }

    const int gr = blockIdx.x * 64 + 16 * w + kg * 4;
#pragma unroll
    for (int ct = 0; ct < 4; ++ct) {
        const int col = ct * 16 + lr;
        if (col < 50) {
#pragma unroll
            for (int rg = 0; rg < 4; ++rg) {
                const int orow = gr + rg;
                if (orow < NN)
                    H[(size_t)orow * 64 + col] = __float2half_rn(acc[ct][rg]);
            }
        }
    }
}

// ---------------- layers 2..5: fp16 X, fp16 hi/lo split MFMA --------------
// A-fragment = raw 16B load from the fp16 activation row (already in MFMA
// order). W tiles pre-transposed/split/pitched by k_wprep; staged by a
// linear conflict-free copy. C = X*Wh + X*Wl, fp32 acc.

template <int FIN, int KP, int PITCH, int SX, int FOUT, int NCT, int S>
__global__ __launch_bounds__(256, 4) void k_matmul_fh(const __half* __restrict__ X,
                                                      const short* __restrict__ wt,
                                                      __half* __restrict__ H) {
    constexpr int NKB = KP / 32;
    constexpr int WCNT = NCT * 16 * PITCH;         // shorts per hi (= per lo)
    __shared__ short lds[2 * WCNT];
    const int t = threadIdx.x;
    {
        const int4* src = (const int4*)wt;
        int4* dst = (int4*)lds;
        constexpr int NI = (2 * WCNT) / 8;
        for (int j = t; j < NI; j += 256) dst[j] = src[j];
    }
    const int w = t >> 6;
    const int lane = t & 63;
    const int lr = lane & 15;
    const int kg = lane >> 4;
    const int row = blockIdx.x * 64 + 16 * w + lr;
    const __half* xr = X + (size_t)(row < NN ? row : NN - 1) * SX + kg * 8;

    int4 xa[NKB];
#pragma unroll
    for (int kb = 0; kb < NKB; ++kb) xa[kb] = *(const int4*)(xr + kb * 32);
    __syncthreads();

    f32x4v acc[NCT];
#pragma unroll
    for (int ct = 0; ct < NCT; ++ct) acc[ct] = (f32x4v){0.f, 0.f, 0.f, 0.f};

#pragma unroll
    for (int kb = 0; kb < NKB; ++kb) {
        f16x8 a = *(const f16x8*)&xa[kb];
        const int kf = kb * 32 + kg * 8;
#pragma unroll
        for (int ct = 0; ct < NCT; ++ct) {
            const int c = ct * 16 + lr;
            f16x8 bh = *(const f16x8*)&lds[c * PITCH + kf];
            f16x8 bl = *(const f16x8*)&lds[WCNT + c * PITCH + kf];
            acc[ct] = __builtin_amdgcn_mfma_f32_16x16x32_f16(a, bh, acc[ct], 0, 0, 0);
            acc[ct] = __builtin_amdgcn_mfma_f32_16x16x32_f16(a, bl, acc[ct], 0, 0, 0);
        }
    }

    const int gr = blockIdx.x * 64 + 16 * w + kg * 4;
#pragma unroll
    for (int ct = 0; ct < NCT; ++ct) {
        const int col = ct * 16 + lr;
        if (col < FOUT) {
#pragma unroll
            for (int rg = 0; rg < 4; ++rg) {
                const int orow = gr + rg;
                if (orow < NN)
                    H[(size_t)orow * S + col] = __float2half_rn(acc[ct][rg]);
            }
        }
    }
}

// ---------------- layer 6 (10 -> 10, VALU) and layer 7 (10 -> 1) ----------

template <int FIN, int SX, int FOUT, int S, int NSPL>
__global__ __launch_bounds__(256, 2) void k_matmul_h(const __half* __restrict__ X,
                                                     const float* __restrict__ W,
                                                     __half* __restrict__ H) {
    constexpr int FC = FOUT / NSPL;
    constexpr int NCH = (FIN + 7) / 8;
    const int node = blockIdx.x * 256 + threadIdx.x;
    const int ch = blockIdx.y;                 // SGPR by construction
    if (node >= NN) return;
    const __half* xr = X + (size_t)node * SX;
    int4 raw[NCH];
#pragma unroll
    for (int c = 0; c < NCH; ++c) raw[c] = *(const int4*)(xr + 8 * c);
    float acc[FC];
#pragma unroll
    for (int j = 0; j < FC; ++j) acc[j] = 0.0f;
#pragma unroll
    for (int c = 0; c < NCH; ++c) {
        const __half2* hp = (const __half2*)&raw[c];
        const int lim = (FIN - 8 * c < 8) ? FIN - 8 * c : 8;  // folds post-unroll
#pragma unroll
        for (int kk = 0; kk < 8; ++kk) {
            if (kk < lim) {
                __half2 pair = hp[kk >> 1];
                float xv = (kk & 1) ? __high2float(pair) : __low2float(pair);
                const float* wrow = W + (8 * c + kk) * FOUT + ch * FC;
#pragma unroll
                for (int j = 0; j < FC; ++j) acc[j] = fmaf(xv, wrow[j], acc[j]);
            }
        }
    }
    __half* hr = H + (size_t)node * S + ch * FC;
#pragma unroll
    for (int j = 0; j < FC; ++j) hr[j] = __float2half_rn(acc[j]);
}

__global__ void k_matmul_1h(const __half* __restrict__ X, const float* __restrict__ W,
                            float* __restrict__ H) {
    int i = blockIdx.x * blockDim.x + threadIdx.x;
    if (i >= NN) return;
    const __half* xr = X + (size_t)i * 16;
    int4 r0 = *(const int4*)xr;                  // halfs 0..7
    __half2 r1 = *(const __half2*)(xr + 8);      // halfs 8,9
    const __half2* hp = (const __half2*)&r0;
    float acc = 0.0f;
#pragma unroll
    for (int q = 0; q < 4; ++q) {
        acc = fmaf(__low2float(hp[q]), W[2 * q], acc);
        acc = fmaf(__high2float(hp[q]), W[2 * q + 1], acc);
    }
    acc = fmaf(__low2float(r1), W[8], acc);
    acc = fmaf(__high2float(r1), W[9], acc);
    H[i] = acc;
}

// ---------------- CSR pull aggregation + fused epilogue (fp16 H) ----------
// Lane handles 4 half2s (one 16B gather per edge). Output stored fp16 at
// stride SA halfs (the next layer's X); pad half2s beyond R are ZEROED so
// downstream MFMA K-pad reads are exact (workspace may be poison).

static __device__ __forceinline__ int2 nt_load2(const int2* p) {
    unsigned long long raw = __builtin_nontemporal_load((const unsigned long long*)p);
    return make_int2((int)(raw & 0xFFFFFFFFull), (int)(raw >> 32));
}

template <int F, int SH, int SA, int LPN, bool RELU>
__global__ __launch_bounds__(256) void k_agg2(const int* __restrict__ offs,
                                              const int2* __restrict__ csw,
                                              const __half2* __restrict__ H,
                                              const float* __restrict__ dinv,
                                              const float* __restrict__ b,
                                              __half* __restrict__ O) {
    constexpr int R = F / 2;               // real half2 count per row
    int t = blockIdx.x * blockDim.x + threadIdx.x;
    int g = t / LPN;
    int f = t - g * LPN;
    if (g >= NN) return;
    const int q0 = 4 * f;                  // first half2 this lane owns
    __half2* orow = (__half2*)(O + (size_t)g * SA) + q0;
    if (q0 >= R) {                         // pad-only lane: zero the pad
        const __half2 z = __floats2half2_rn(0.f, 0.f);
#pragma unroll
        for (int c = 0; c < 4; ++c)
            if (q0 + c < SA / 2) orow[c] = z;
        return;
    }
    int p = offs[g];
    const int pe = offs[g + 1];
    const int pl = pe - 1;

    float2 acc[4];
#pragma unroll
    for (int c = 0; c < 4; ++c) acc[c] = make_float2(0.f, 0.f);

    for (; p < pe; p += 4) {
        int2 e[4];
#pragma unroll
        for (int i = 0; i < 4; ++i) e[i] = nt_load2(csw + min(p + i, pl));
        __half2 h[4][4];
#pragma unroll
        for (int i = 0; i < 4; ++i)
            *(int4*)h[i] = *(const int4*)(H + (size_t)e[i].x * SH + q0);
#pragma unroll
        for (int i = 0; i < 4; ++i) {
            float w = (p + i < pe) ? __int_as_float(e[i].y) : 0.0f;
#pragma unroll
            for (int c = 0; c < 4; ++c) {
                acc[c].x = fmaf(__low2float(h[i][c]), w, acc[c].x);
                acc[c].y = fmaf(__high2float(h[i][c]), w, acc[c].y);
            }
        }
    }

    float di = dinv[g];
    float d2 = di * di;
    __half2 hs[4];
    *(int4*)hs = *(const int4*)(H + (size_t)g * SH + q0);
#pragma unroll
    for (int c = 0; c < 4; ++c) {
        if (q0 + c < R) {
            float vx = acc[c].x + fmaf(__low2float(hs[c]), d2, b[2 * (q0 + c)]);
            float vy = acc[c].y + fmaf(__high2float(hs[c]), d2, b[2 * (q0 + c) + 1]);
            if (RELU) { vx = fmaxf(vx, 0.f); vy = fmaxf(vy, 0.f); }
            orow[c] = __floats2half2_rn(vx, vy);
        } else if (q0 + c < SA / 2) {
            orow[c] = __floats2half2_rn(0.f, 0.f);   // zero pad tail
        }
    }
}

// F=1 aggregation (final layer, fp32 H): one thread per node, predicated 4-wide.
__global__ void k_agg1(const int* __restrict__ offs, const int2* __restrict__ csw,
                       const float* __restrict__ H, const float* __restrict__ dinv,
                       const float* __restrict__ b, float* __restrict__ O) {
    int g = blockIdx.x * blockDim.x + threadIdx.x;
    if (g >= NN) return;
    int p = offs[g];
    const int pe = offs[g + 1];
    const int pl = pe - 1;
    float a0 = 0.f, a1 = 0.f, a2 = 0.f, a3 = 0.f;
    for (; p < pe; p += 4) {
        int2 e0 = nt_load2(csw + min(p, pl)),     e1 = nt_load2(csw + min(p + 1, pl));
        int2 e2 = nt_load2(csw + min(p + 2, pl)), e3 = nt_load2(csw + min(p + 3, pl));
        float w0 = (p < pe)     ? __int_as_float(e0.y) : 0.f;
        float w1 = (p + 1 < pe) ? __int_as_float(e1.y) : 0.f;
        float w2 = (p + 2 < pe) ? __int_as_float(e2.y) : 0.f;
        float w3 = (p + 3 < pe) ? __int_as_float(e3.y) : 0.f;
        a0 = fmaf(H[e0.x], w0, a0);
        a1 = fmaf(H[e1.x], w1, a1);
        a2 = fmaf(H[e2.x], w2, a2);
        a3 = fmaf(H[e3.x], w3, a3);
    }
    float di = dinv[g];
    O[g] = ((a0 + a1) + (a2 + a3)) + fmaf(H[g], di * di, b[0]);
}

// ---------------- launch ----------------

static inline size_t alignup(size_t x) { return (x + 255) & ~(size_t)255; }

extern "C" void kernel_launch(void* const* d_in, const int* in_sizes, int n_in,
                              void* d_out, int out_size, void* d_ws, size_t ws_size,
                              hipStream_t stream) {
    const float* x  = (const float*)d_in[0];
    const int*   ei = (const int*)d_in[1];
    const float* ew = (const float*)d_in[2];
    const float* Wp[7];
    const float* Bp[7];
    for (int l = 0; l < 7; ++l) {
        Wp[l] = (const float*)d_in[3 + 2 * l];
        Bp[l] = (const float*)d_in[4 + 2 * l];
    }
    const int* row = ei;       // source
    const int* col = ei + NE;  // destination

    // workspace carve (~70 MB); Hb/Aa/Ab fp16, stride <= 64 halfs
    char* ws = (char*)d_ws;
    float* dinv  = (float*)ws;  ws += alignup((size_t)NN * 4);
    char*  Hb    = ws;          ws += alignup((size_t)NN * 64 * 2);
    char*  Aa    = ws;          ws += alignup((size_t)NN * 64 * 2);
    char*  Ab    = ws;          ws += alignup((size_t)NN * 64 * 2);
    int*   offs  = (int*)ws;    ws += alignup((size_t)(NN + 1) * 4);
    int*   counts= (int*)ws;    ws += alignup((size_t)NBUK * EB * 4);
    int*   btot  = (int*)ws;    ws += alignup((size_t)NBUK * 4);
    int*   bstart= (int*)ws;    ws += alignup((size_t)(NBUK + 1) * 4);
    int2*  stg   = (int2*)ws;   ws += alignup((size_t)NE * 8);
    int2*  csw   = (int2*)ws;   ws += alignup((size_t)NE * 8);
    short* wt    = (short*)ws;  ws += alignup((size_t)WT_TOT * 2);

    const int gN = (NN + 255) / 256;
    const int gM = (NN + 63) / 64;     // 64-row MFMA tiles

    // W prep (tiny) + CSR build — no global atomics, no 1-block O(N) scans
    k_wprep<<<1, 256, 0, stream>>>(Wp[0], Wp[1], Wp[2], Wp[3], Wp[4], wt);
    k_hist0<<<EB, 256, 0, stream>>>(col, counts);
    k_scanA<<<NBUK, 256, 0, stream>>>(counts, btot);
    k_scanB<<<1, 256, 0, stream>>>(btot, bstart);
    k_A1<<<EB, 256, 0, stream>>>(row, col, ew, counts, bstart, stg);
    k_bdeg<<<NBUK, 256, 0, stream>>>(bstart, stg, dinv);
    k_place<<<NBUK, 512, 0, stream>>>(bstart, stg, dinv, offs, csw);

#define AGG(FOUT, S, LPN, RELU, OUT, LIDX)                                                  \
    k_agg2<FOUT, (S) / 2, S, LPN, RELU>                                                     \
        <<<((size_t)NN * (LPN) + 255) / 256, 256, 0, stream>>>(                             \
            offs, csw, (const __half2*)Hb, dinv, Bp[LIDX], (__half*)(OUT))

    // layer 1: fp32 x input, bf16 split MFMA (W pre-staged, X direct)
    k_matmul_f<<<gM, 256, 0, stream>>>(x, wt, (__half*)Hb);
    AGG(50, 64, 8, true, Aa, 0);
    // layers 2..5: fp16 MFMA (hi/lo split W)
    k_matmul_fh<50, 64, 72, 64, 50, 4, 64><<<gM, 256, 0, stream>>>((const __half*)Aa, wt + WT2, (__half*)Hb);
    AGG(50, 64, 8, true, Ab, 1);
    k_matmul_fh<50, 64, 72, 64, 30, 2, 32><<<gM, 256, 0, stream>>>((const __half*)Ab, wt + WT3, (__half*)Hb);
    AGG(30, 32, 4, true, Aa, 2);
    k_matmul_fh<30, 32, 40, 32, 30, 2, 32><<<gM, 256, 0, stream>>>((const __half*)Aa, wt + WT4, (__half*)Hb);
    AGG(30, 32, 4, true, Ab, 3);
    k_matmul_fh<30, 32, 40, 32, 10, 1, 16><<<gM, 256, 0, stream>>>((const __half*)Ab, wt + WT5, (__half*)Hb);
    AGG(10, 16, 2, true, Aa, 4);
    // layer 6: 10 -> 10 VALU (wrong shape for K>=32 MFMA fragments)
    k_matmul_h<10, 16, 10, 16, 1><<<dim3(gN, 1), 256, 0, stream>>>((const __half*)Aa, Wp[5], (__half*)Hb);
    AGG(10, 16, 2, true, Ab, 5);
#undef AGG

    // layer 7: 10 -> 1, no relu, fp32 H, fp32 output
    k_matmul_1h<<<gN, 256, 0, stream>>>((const __half*)Ab, Wp[6], (float*)Hb);
    k_agg1<<<gN, 256, 0, stream>>>(offs, csw, (const float*)Hb, dinv, Bp[6],
                                   (float*)d_out);
}

// Round 9
// 418.429 us; speedup vs baseline: 2.7326x; 1.0564x over previous
//
#include <hip/hip_runtime.h>
#include <hip/hip_fp16.h>

// GCN, 7 layers: h = relu(Â (h W) + b), Â = D^-1/2 (A + I) D^-1/2.
// Round 24: aggregation ILP. Accounting: after the MFMA ports (r22: -22us,
// r23: -15.7us, both matching prediction) every kernel is <42us and the 7
// agg dispatches must hold ~250-300us of the 442us total (~30-40us each =
// ~1.1 TB/s effective on ~38MB/layer -> gather-LATENCY-bound, not BW-bound:
// only 4 independent H-gathers in flight per lane, each dependent on a csw
// record load). Fix (pure ILP, no restructure per r16/r17 lessons):
//  (a) k_agg2/k_agg1 process 8 edges per iteration (8 rec loads + 8 gathers
//      in flight; +~40 VGPR, still fine at 256 thr).
//  (b) k_wprep parallelized across 6 blocks (was a serial 1-block prelude).
// Everything else byte-identical to round 23 (442.0us measured).

static constexpr int NN = 100000;
static constexpr int NE = 1600000;
static constexpr int BKL = 9;                      // 512 nodes per bucket
static constexpr int NBUK = (NN + 511) >> BKL;     // 196 buckets
static constexpr int EPT = 8;                      // edges per thread (hist/A1)
static constexpr int EB = (NE + 2047) / 2048;      // 782 edge blocks

// ---------------- 1. bucket histogram (LDS only) ----------------

__global__ __launch_bounds__(256) void k_hist0(const int* __restrict__ col,
                                               int* __restrict__ counts) {
    __shared__ int lh[NBUK];
    for (int j = threadIdx.x; j < NBUK; j += 256) lh[j] = 0;
    __syncthreads();
    int base = blockIdx.x * 2048;
#pragma unroll
    for (int k = 0; k < EPT; ++k) {
        int e = base + k * 256 + threadIdx.x;
        if (e < NE) atomicAdd(&lh[col[e] >> BKL], 1);
    }
    __syncthreads();
    for (int j = threadIdx.x; j < NBUK; j += 256)
        counts[j * EB + blockIdx.x] = lh[j];  // bucket-major
}

// ---------------- 2a. per-bucket scan (196 parallel blocks) ----------------

__global__ __launch_bounds__(256) void k_scanA(int* __restrict__ counts,
                                               int* __restrict__ btot) {
    __shared__ int lds[256];
    const int b = blockIdx.x;
    const int t = threadIdx.x;
    int* c = counts + (size_t)b * EB;
    constexpr int PER = (EB + 255) / 256;  // 4
    int v[PER];
    int s = 0;
#pragma unroll
    for (int k = 0; k < PER; ++k) {
        int idx = t * PER + k;
        v[k] = (idx < EB) ? c[idx] : 0;
        s += v[k];
    }
    lds[t] = s;
    __syncthreads();
    for (int off = 1; off < 256; off <<= 1) {
        int u = (t >= off) ? lds[t - off] : 0;
        __syncthreads();
        lds[t] += u;
        __syncthreads();
    }
    int run = lds[t] - s;
#pragma unroll
    for (int k = 0; k < PER; ++k) {
        int idx = t * PER + k;
        if (idx < EB) { c[idx] = run; run += v[k]; }
    }
    if (t == 255) btot[b] = lds[255];
}

// ---------------- 2b. scan of 196 bucket totals -> bstart ----------------

__global__ void k_scanB(const int* __restrict__ btot, int* __restrict__ bstart) {
    __shared__ int lds[256];
    int t = threadIdx.x;
    int v = (t < NBUK) ? btot[t] : 0;
    lds[t] = v;
    __syncthreads();
    for (int off = 1; off < 256; off <<= 1) {
        int u = (t >= off) ? lds[t - off] : 0;
        __syncthreads();
        lds[t] += u;
        __syncthreads();
    }
    if (t < NBUK) bstart[t] = lds[t] - v;  // exclusive
    if (t == 0) bstart[NBUK] = NE;
}

// ---------------- 3. stage records, bucket-grouped (LDS cursors) ----------

__global__ __launch_bounds__(256) void k_A1(const int* __restrict__ row,
                                            const int* __restrict__ col,
                                            const float* __restrict__ ew,
                                            const int* __restrict__ counts,
                                            const int* __restrict__ bstart,
                                            int2* __restrict__ stg) {
    __shared__ int cur[NBUK];
    for (int j = threadIdx.x; j < NBUK; j += 256)
        cur[j] = bstart[j] + counts[j * EB + blockIdx.x];
    __syncthreads();
    int base = blockIdx.x * 2048;
#pragma unroll
    for (int k = 0; k < EPT; ++k) {
        int e = base + k * 256 + threadIdx.x;
        if (e < NE) {
            int c = col[e], r = row[e];
            int pos = atomicAdd(&cur[c >> BKL], 1);  // LDS atomic
            stg[pos] = make_int2(((c & 511) << 17) | r, __float_as_int(ew[e]));
        }
    }
}

// ---------------- 4. per-bucket degree -> dinv (plain stores) ----------

__global__ __launch_bounds__(256) void k_bdeg(const int* __restrict__ bstart,
                                              const int2* __restrict__ stg,
                                              float* __restrict__ dinv) {
    __shared__ float sdeg[512];
    const int b = blockIdx.x;
    for (int j = threadIdx.x; j < 512; j += 256) sdeg[j] = 0.0f;
    __syncthreads();
    const int s = bstart[b], e = bstart[b + 1];
    for (int p = s + threadIdx.x; p < e; p += 256) {
        int2 rec = stg[p];
        atomicAdd(&sdeg[rec.x >> 17], __int_as_float(rec.y));
    }
    __syncthreads();
    for (int j = threadIdx.x; j < 512; j += 256) {
        int idx = (b << BKL) + j;
        if (idx < NN) dinv[idx] = rsqrtf(sdeg[j] + 1.0f);  // +1 self-loop
    }
}

// ---------------- 5. per-bucket placement: offs + csw (LDS scan) ----------

__global__ __launch_bounds__(512) void k_place(const int* __restrict__ bstart,
                                               const int2* __restrict__ stg,
                                               const float* __restrict__ dinv,
                                               int* __restrict__ offs,
                                               int2* __restrict__ csw) {
    __shared__ int lcnt[512];
    __shared__ int cur[512];
    const int b = blockIdx.x;
    const int t = threadIdx.x;
    lcnt[t] = 0;
    __syncthreads();
    const int s = bstart[b], e = bstart[b + 1];
    for (int p = s + t; p < e; p += 512)
        atomicAdd(&lcnt[stg[p].x >> 17], 1);
    __syncthreads();
    int v = lcnt[t];
    for (int off = 1; off < 512; off <<= 1) {   // inclusive Hillis-Steele
        int u = (t >= off) ? lcnt[t - off] : 0;
        __syncthreads();
        lcnt[t] += u;
        __syncthreads();
    }
    int excl = lcnt[t] - v;
    int idx = (b << BKL) + t;
    if (idx <= NN) offs[idx] = s + excl;        // covers offs[NN] exactly once
    cur[t] = s + excl;
    __syncthreads();
    for (int p = s + t; p < e; p += 512) {
        int2 rec = stg[p];
        int cl = rec.x >> 17;
        int r = rec.x & 0x1FFFF;
        float nw = dinv[r] * __int_as_float(rec.y) * dinv[(b << BKL) + cl];
        int slot = atomicAdd(&cur[cl], 1);      // LDS atomic
        csw[slot] = make_int2(r, __float_as_int(nw));
    }
}

// ---------------- weight prep (6 small blocks, runs once per graph) -------

typedef short s16x8 __attribute__((ext_vector_type(8)));
typedef float f32x4v __attribute__((ext_vector_type(4)));
typedef _Float16 f16x8 __attribute__((ext_vector_type(8)));

static __device__ __forceinline__ unsigned short bf16rn(float f) {
    unsigned u = __float_as_uint(f);
    return (unsigned short)((u + 0x7FFFu + ((u >> 16) & 1u)) >> 16);
}

// wt layout (shorts):
//  [0, 16384)      layer-1 bf16 hi|lo, transposed, XOR-swizzled (round-22)
//  [WT2..) fp16 hi|lo transposed tiles, pitch-padded, for layers 2..5
static constexpr int WT2 = 16384;                  // 64c x 72p x2 = 9216
static constexpr int WT3 = WT2 + 9216;             // 32c x 72p x2 = 4608
static constexpr int WT4 = WT3 + 4608;             // 32c x 40p x2 = 2560
static constexpr int WT5 = WT4 + 2560;             // 16c x 40p x2 = 1280
static constexpr int WT_TOT = WT5 + 1280;

static __device__ __forceinline__ void prep_f16(const float* __restrict__ W,
                                                int FIN, int FOUT, int KP,
                                                int PITCH, int NCT,
                                                short* __restrict__ dst, int t) {
    const int WCNT = NCT * 16 * PITCH;
    for (int li = t; li < NCT * 16 * KP; li += 256) {
        const int c = li / KP, k = li - c * KP;
        float f = (c < FOUT && k < FIN) ? W[k * FOUT + c] : 0.f;
        __half hh = __float2half_rn(f);
        __half hl = __float2half_rn(f - __half2float(hh));
        dst[c * PITCH + k] = __half_as_short(hh);
        dst[WCNT + c * PITCH + k] = __half_as_short(hl);
    }
}

__global__ void k_wprep(const float* __restrict__ W0, const float* __restrict__ W1,
                        const float* __restrict__ W2, const float* __restrict__ W3,
                        const float* __restrict__ W4, short* __restrict__ wt) {
    const int t = threadIdx.x;
    const int blk = blockIdx.x;
    if (blk < 2) {
        // layer-1 bf16 split (unchanged layout), halved across blocks 0,1
#pragma unroll
        for (int i = 0; i < 16; ++i) {
            const int li = t + 256 * (16 * blk + i);   // 0..8191
            const int c = li >> 7, k = li & 127;
            float f = (c < 50) ? W0[k * 50 + c] : 0.f;
            unsigned short hb = bf16rn(f);
            float hf = __uint_as_float((unsigned)hb << 16);
            unsigned short lb = bf16rn(f - hf);
            const int off = c * 128 + (k ^ ((c & 7) << 3));
            wt[off] = (short)hb;
            wt[8192 + off] = (short)lb;
        }
    } else if (blk == 2) prep_f16(W1, 50, 50, 64, 72, 4, wt + WT2, t);
    else if (blk == 3)   prep_f16(W2, 50, 30, 64, 72, 2, wt + WT3, t);
    else if (blk == 4)   prep_f16(W3, 30, 30, 32, 40, 2, wt + WT4, t);
    else                 prep_f16(W4, 30, 10, 32, 40, 1, wt + WT5, t);
}

// ---------------- layer 1: fp32 X, bf16 split MFMA (round-22, verified) ---

__global__ __launch_bounds__(256, 4) void k_matmul_f(const float* __restrict__ X,
                                                     const short* __restrict__ wt,
                                                     __half* __restrict__ H) {
    __shared__ short lds[2 * 64 * 128];           // Wt hi | lo, pre-swizzled, 32 KB
    const int t = threadIdx.x;
    {
        const int4* src = (const int4*)wt;
        int4* dst = (int4*)lds;
#pragma unroll
        for (int j = 0; j < 8; ++j) dst[j * 256 + t] = src[j * 256 + t];
    }
    const int w = t >> 6;
    const int lane = t & 63;
    const int lr = lane & 15;
    const int kg = lane >> 4;
    const int row = blockIdx.x * 64 + 16 * w + lr;
    const float* xr = X + (size_t)(row < NN ? row : NN - 1) * 128 + kg * 8;

    float4 xa[4][2];
#pragma unroll
    for (int kb = 0; kb < 4; ++kb) {
        xa[kb][0] = *(const float4*)(xr + kb * 32);
        xa[kb][1] = *(const float4*)(xr + kb * 32 + 4);
    }
    __syncthreads();

    f32x4v acc[4];
#pragma unroll
    for (int ct = 0; ct < 4; ++ct) acc[ct] = (f32x4v){0.f, 0.f, 0.f, 0.f};

#pragma unroll
    for (int kb = 0; kb < 4; ++kb) {
        s16x8 ah, al;
        const unsigned* xu = (const unsigned*)&xa[kb][0];
#pragma unroll
        for (int e = 0; e < 8; ++e) {
            const unsigned u = xu[e];
            const float lo = __uint_as_float(u) - __uint_as_float(u & 0xFFFF0000u);
            ah[e] = (short)(u >> 16);
            al[e] = (short)(__float_as_uint(lo) >> 16);
        }
        const int kf = kb * 32 + kg * 8;
        s16x8 bh[4], bl[4];
#pragma unroll
        for (int ct = 0; ct < 4; ++ct) {
            const int bc = ct * 16 + lr;
            const int ko = bc * 128 + (kf ^ ((bc & 7) << 3));
            bh[ct] = *(const s16x8*)&lds[ko];
            bl[ct] = *(const s16x8*)&lds[8192 + ko];
        }
#pragma unroll
        for (int ct = 0; ct < 4; ++ct)
            acc[ct] = __builtin_amdgcn_mfma_f32_16x16x32_bf16(ah, bh[ct], acc[ct], 0, 0, 0);
#pragma unroll
        for (int ct = 0; ct < 4; ++ct)
            acc[ct] = __builtin_amdgcn_mfma_f32_16x16x32_bf16(ah, bl[ct], acc[ct], 0, 0, 0);
#pragma unroll
        for (int ct = 0; ct < 4; ++ct)
            acc[ct] = __builtin_amdgcn_mfma_f32_16x16x32_bf16(al, bh[ct], acc[ct], 0, 0, 0);
    }

    const int gr = blockIdx.x * 64 + 16 * w + kg * 4;
#pragma unroll
    for (int ct = 0; ct < 4; ++ct) {
        const int col = ct * 16 + lr;
        if (col < 50) {
#pragma unroll
            for (int rg = 0; rg < 4; ++rg) {
                const int orow = gr + rg;
                if (orow < NN)
                    H[(size_t)orow * 64 + col] = __float2half_rn(acc[ct][rg]);
            }
        }
    }
}

// ---------------- layers 2..5: fp16 X, fp16 hi/lo split MFMA --------------

template <int FIN, int KP, int PITCH, int SX, int FOUT, int NCT, int S>
__global__ __launch_bounds__(256, 4) void k_matmul_fh(const __half* __restrict__ X,
                                                      const short* __restrict__ wt,
                                                      __half* __restrict__ H) {
    constexpr int NKB = KP / 32;
    constexpr int WCNT = NCT * 16 * PITCH;         // shorts per hi (= per lo)
    __shared__ short lds[2 * WCNT];
    const int t = threadIdx.x;
    {
        const int4* src = (const int4*)wt;
        int4* dst = (int4*)lds;
        constexpr int NI = (2 * WCNT) / 8;
        for (int j = t; j < NI; j += 256) dst[j] = src[j];
    }
    const int w = t >> 6;
    const int lane = t & 63;
    const int lr = lane & 15;
    const int kg = lane >> 4;
    const int row = blockIdx.x * 64 + 16 * w + lr;
    const __half* xr = X + (size_t)(row < NN ? row : NN - 1) * SX + kg * 8;

    int4 xa[NKB];
#pragma unroll
    for (int kb = 0; kb < NKB; ++kb) xa[kb] = *(const int4*)(xr + kb * 32);
    __syncthreads();

    f32x4v acc[NCT];
#pragma unroll
    for (int ct = 0; ct < NCT; ++ct) acc[ct] = (f32x4v){0.f, 0.f, 0.f, 0.f};

#pragma unroll
    for (int kb = 0; kb < NKB; ++kb) {
        f16x8 a = *(const f16x8*)&xa[kb];
        const int kf = kb * 32 + kg * 8;
#pragma unroll
        for (int ct = 0; ct < NCT; ++ct) {
            const int c = ct * 16 + lr;
            f16x8 bh = *(const f16x8*)&lds[c * PITCH + kf];
            f16x8 bl = *(const f16x8*)&lds[WCNT + c * PITCH + kf];
            acc[ct] = __builtin_amdgcn_mfma_f32_16x16x32_f16(a, bh, acc[ct], 0, 0, 0);
            acc[ct] = __builtin_amdgcn_mfma_f32_16x16x32_f16(a, bl, acc[ct], 0, 0, 0);
        }
    }

    const int gr = blockIdx.x * 64 + 16 * w + kg * 4;
#pragma unroll
    for (int ct = 0; ct < NCT; ++ct) {
        const int col = ct * 16 + lr;
        if (col < FOUT) {
#pragma unroll
            for (int rg = 0; rg < 4; ++rg) {
                const int orow = gr + rg;
                if (orow < NN)
                    H[(size_t)orow * S + col] = __float2half_rn(acc[ct][rg]);
            }
        }
    }
}

// ---------------- layer 6 (10 -> 10, VALU) and layer 7 (10 -> 1) ----------

template <int FIN, int SX, int FOUT, int S, int NSPL>
__global__ __launch_bounds__(256, 2) void k_matmul_h(const __half* __restrict__ X,
                                                     const float* __restrict__ W,
                                                     __half* __restrict__ H) {
    constexpr int FC = FOUT / NSPL;
    constexpr int NCH = (FIN + 7) / 8;
    const int node = blockIdx.x * 256 + threadIdx.x;
    const int ch = blockIdx.y;                 // SGPR by construction
    if (node >= NN) return;
    const __half* xr = X + (size_t)node * SX;
    int4 raw[NCH];
#pragma unroll
    for (int c = 0; c < NCH; ++c) raw[c] = *(const int4*)(xr + 8 * c);
    float acc[FC];
#pragma unroll
    for (int j = 0; j < FC; ++j) acc[j] = 0.0f;
#pragma unroll
    for (int c = 0; c < NCH; ++c) {
        const __half2* hp = (const __half2*)&raw[c];
        const int lim = (FIN - 8 * c < 8) ? FIN - 8 * c : 8;  // folds post-unroll
#pragma unroll
        for (int kk = 0; kk < 8; ++kk) {
            if (kk < lim) {
                __half2 pair = hp[kk >> 1];
                float xv = (kk & 1) ? __high2float(pair) : __low2float(pair);
                const float* wrow = W + (8 * c + kk) * FOUT + ch * FC;
#pragma unroll
                for (int j = 0; j < FC; ++j) acc[j] = fmaf(xv, wrow[j], acc[j]);
            }
        }
    }
    __half* hr = H + (size_t)node * S + ch * FC;
#pragma unroll
    for (int j = 0; j < FC; ++j) hr[j] = __float2half_rn(acc[j]);
}

__global__ void k_matmul_1h(const __half* __restrict__ X, const float* __restrict__ W,
                            float* __restrict__ H) {
    int i = blockIdx.x * blockDim.x + threadIdx.x;
    if (i >= NN) return;
    const __half* xr = X + (size_t)i * 16;
    int4 r0 = *(const int4*)xr;                  // halfs 0..7
    __half2 r1 = *(const __half2*)(xr + 8);      // halfs 8,9
    const __half2* hp = (const __half2*)&r0;
    float acc = 0.0f;
#pragma unroll
    for (int q = 0; q < 4; ++q) {
        acc = fmaf(__low2float(hp[q]), W[2 * q], acc);
        acc = fmaf(__high2float(hp[q]), W[2 * q + 1], acc);
    }
    acc = fmaf(__low2float(r1), W[8], acc);
    acc = fmaf(__high2float(r1), W[9], acc);
    H[i] = acc;
}

// ---------------- CSR pull aggregation + fused epilogue (fp16 H) ----------
// 8-edge batches: 8 record loads + 8 row gathers in flight per lane
// (latency hiding). Pad half2s beyond R zeroed (MFMA K-pad correctness).

static __device__ __forceinline__ int2 nt_load2(const int2* p) {
    unsigned long long raw = __builtin_nontemporal_load((const unsigned long long*)p);
    return make_int2((int)(raw & 0xFFFFFFFFull), (int)(raw >> 32));
}

template <int F, int SH, int SA, int LPN, bool RELU>
__global__ __launch_bounds__(256) void k_agg2(const int* __restrict__ offs,
                                              const int2* __restrict__ csw,
                                              const __half2* __restrict__ H,
                                              const float* __restrict__ dinv,
                                              const float* __restrict__ b,
                                              __half* __restrict__ O) {
    constexpr int R = F / 2;               // real half2 count per row
    int t = blockIdx.x * blockDim.x + threadIdx.x;
    int g = t / LPN;
    int f = t - g * LPN;
    if (g >= NN) return;
    const int q0 = 4 * f;                  // first half2 this lane owns
    __half2* orow = (__half2*)(O + (size_t)g * SA) + q0;
    if (q0 >= R) {                         // pad-only lane: zero the pad
        const __half2 z = __floats2half2_rn(0.f, 0.f);
#pragma unroll
        for (int c = 0; c < 4; ++c)
            if (q0 + c < SA / 2) orow[c] = z;
        return;
    }
    int p = offs[g];
    const int pe = offs[g + 1];
    const int pl = pe - 1;

    float2 acc[4];
#pragma unroll
    for (int c = 0; c < 4; ++c) acc[c] = make_float2(0.f, 0.f);

    for (; p < pe; p += 8) {
        int2 e[8];
#pragma unroll
        for (int i = 0; i < 8; ++i) e[i] = nt_load2(csw + min(p + i, pl));
        __half2 h[8][4];
#pragma unroll
        for (int i = 0; i < 8; ++i)
            *(int4*)h[i] = *(const int4*)(H + (size_t)e[i].x * SH + q0);
#pragma unroll
        for (int i = 0; i < 8; ++i) {
            float w = (p + i < pe) ? __int_as_float(e[i].y) : 0.0f;
#pragma unroll
            for (int c = 0; c < 4; ++c) {
                acc[c].x = fmaf(__low2float(h[i][c]), w, acc[c].x);
                acc[c].y = fmaf(__high2float(h[i][c]), w, acc[c].y);
            }
        }
    }

    float di = dinv[g];
    float d2 = di * di;
    __half2 hs[4];
    *(int4*)hs = *(const int4*)(H + (size_t)g * SH + q0);
#pragma unroll
    for (int c = 0; c < 4; ++c) {
        if (q0 + c < R) {
            float vx = acc[c].x + fmaf(__low2float(hs[c]), d2, b[2 * (q0 + c)]);
            float vy = acc[c].y + fmaf(__high2float(hs[c]), d2, b[2 * (q0 + c) + 1]);
            if (RELU) { vx = fmaxf(vx, 0.f); vy = fmaxf(vy, 0.f); }
            orow[c] = __floats2half2_rn(vx, vy);
        } else if (q0 + c < SA / 2) {
            orow[c] = __floats2half2_rn(0.f, 0.f);   // zero pad tail
        }
    }
}

// F=1 aggregation (final layer, fp32 H): 8-wide predicated batches.
__global__ void k_agg1(const int* __restrict__ offs, const int2* __restrict__ csw,
                       const float* __restrict__ H, const float* __restrict__ dinv,
                       const float* __restrict__ b, float* __restrict__ O) {
    int g = blockIdx.x * blockDim.x + threadIdx.x;
    if (g >= NN) return;
    int p = offs[g];
    const int pe = offs[g + 1];
    const int pl = pe - 1;
    float a[8];
#pragma unroll
    for (int i = 0; i < 8; ++i) a[i] = 0.f;
    for (; p < pe; p += 8) {
        int2 e[8];
#pragma unroll
        for (int i = 0; i < 8; ++i) e[i] = nt_load2(csw + min(p + i, pl));
        float hv[8];
#pragma unroll
        for (int i = 0; i < 8; ++i) hv[i] = H[e[i].x];
#pragma unroll
        for (int i = 0; i < 8; ++i) {
            float w = (p + i < pe) ? __int_as_float(e[i].y) : 0.f;
            a[i] = fmaf(hv[i], w, a[i]);
        }
    }
    float di = dinv[g];
    float s = ((a[0] + a[1]) + (a[2] + a[3])) + ((a[4] + a[5]) + (a[6] + a[7]));
    O[g] = s + fmaf(H[g], di * di, b[0]);
}

// ---------------- launch ----------------

static inline size_t alignup(size_t x) { return (x + 255) & ~(size_t)255; }

extern "C" void kernel_launch(void* const* d_in, const int* in_sizes, int n_in,
                              void* d_out, int out_size, void* d_ws, size_t ws_size,
                              hipStream_t stream) {
    const float* x  = (const float*)d_in[0];
    const int*   ei = (const int*)d_in[1];
    const float* ew = (const float*)d_in[2];
    const float* Wp[7];
    const float* Bp[7];
    for (int l = 0; l < 7; ++l) {
        Wp[l] = (const float*)d_in[3 + 2 * l];
        Bp[l] = (const float*)d_in[4 + 2 * l];
    }
    const int* row = ei;       // source
    const int* col = ei + NE;  // destination

    // workspace carve (~70 MB); Hb/Aa/Ab fp16, stride <= 64 halfs
    char* ws = (char*)d_ws;
    float* dinv  = (float*)ws;  ws += alignup((size_t)NN * 4);
    char*  Hb    = ws;          ws += alignup((size_t)NN * 64 * 2);
    char*  Aa    = ws;          ws += alignup((size_t)NN * 64 * 2);
    char*  Ab    = ws;          ws += alignup((size_t)NN * 64 * 2);
    int*   offs  = (int*)ws;    ws += alignup((size_t)(NN + 1) * 4);
    int*   counts= (int*)ws;    ws += alignup((size_t)NBUK * EB * 4);
    int*   btot  = (int*)ws;    ws += alignup((size_t)NBUK * 4);
    int*   bstart= (int*)ws;    ws += alignup((size_t)(NBUK + 1) * 4);
    int2*  stg   = (int2*)ws;   ws += alignup((size_t)NE * 8);
    int2*  csw   = (int2*)ws;   ws += alignup((size_t)NE * 8);
    short* wt    = (short*)ws;  ws += alignup((size_t)WT_TOT * 2);

    const int gN = (NN + 255) / 256;
    const int gM = (NN + 63) / 64;     // 64-row MFMA tiles

    // W prep (6 small blocks) + CSR build — no global atomics
    k_wprep<<<6, 256, 0, stream>>>(Wp[0], Wp[1], Wp[2], Wp[3], Wp[4], wt);
    k_hist0<<<EB, 256, 0, stream>>>(col, counts);
    k_scanA<<<NBUK, 256, 0, stream>>>(counts, btot);
    k_scanB<<<1, 256, 0, stream>>>(btot, bstart);
    k_A1<<<EB, 256, 0, stream>>>(row, col, ew, counts, bstart, stg);
    k_bdeg<<<NBUK, 256, 0, stream>>>(bstart, stg, dinv);
    k_place<<<NBUK, 512, 0, stream>>>(bstart, stg, dinv, offs, csw);

#define AGG(FOUT, S, LPN, RELU, OUT, LIDX)                                                  \
    k_agg2<FOUT, (S) / 2, S, LPN, RELU>                                                     \
        <<<((size_t)NN * (LPN) + 255) / 256, 256, 0, stream>>>(                             \
            offs, csw, (const __half2*)Hb, dinv, Bp[LIDX], (__half*)(OUT))

    // layer 1: fp32 x input, bf16 split MFMA (W pre-staged, X direct)
    k_matmul_f<<<gM, 256, 0, stream>>>(x, wt, (__half*)Hb);
    AGG(50, 64, 8, true, Aa, 0);
    // layers 2..5: fp16 MFMA (hi/lo split W)
    k_matmul_fh<50, 64, 72, 64, 50, 4, 64><<<gM, 256, 0, stream>>>((const __half*)Aa, wt + WT2, (__half*)Hb);
    AGG(50, 64, 8, true, Ab, 1);
    k_matmul_fh<50, 64, 72, 64, 30, 2, 32><<<gM, 256, 0, stream>>>((const __half*)Ab, wt + WT3, (__half*)Hb);
    AGG(30, 32, 4, true, Aa, 2);
    k_matmul_fh<30, 32, 40, 32, 30, 2, 32><<<gM, 256, 0, stream>>>((const __half*)Aa, wt + WT4, (__half*)Hb);
    AGG(30, 32, 4, true, Ab, 3);
    k_matmul_fh<30, 32, 40, 32, 10, 1, 16><<<gM, 256, 0, stream>>>((const __half*)Ab, wt + WT5, (__half*)Hb);
    AGG(10, 16, 2, true, Aa, 4);
    // layer 6: 10 -> 10 VALU (wrong shape for K>=32 MFMA fragments)
    k_matmul_h<10, 16, 10, 16, 1><<<dim3(gN, 1), 256, 0, stream>>>((const __half*)Aa, Wp[5], (__half*)Hb);
    AGG(10, 16, 2, true, Ab, 5);
#undef AGG

    // layer 7: 10 -> 1, no relu, fp32 H, fp32 output
    k_matmul_1h<<<gN, 256, 0, stream>>>((const __half*)Ab, Wp[6], (float*)Hb);
    k_agg1<<<gN, 256, 0, stream>>>(offs, csw, (const float*)Hb, dinv, Bp[6],
                                   (float*)d_out);
}